// Round 4
// baseline (570.724 us; speedup 1.0000x reference)
//
#include <hip/hip_runtime.h>
#include <math.h>

// ---------------------------------------------------------------------------
// SNAT3: 4-layer GAT GNN. N=50000, E=800000, HID=64, fp32.
// R11: k-split dense kernels. Lessons baked in:
//  - R9: vmem does NOT dedup same-address lanes -> weights must be LDS.
//  - R8: s_load + ds_read share lgkmcnt (SMEM o-o-o) -> full drains. No SMEM
//    in hot loops.
//  - R10: 128-node blocks -> 391 blocks -> 1.5 blk/CU -> occupancy 14%,
//    latency-bound. Need 64-node blocks (782 -> ~3 blk/CU).
//  Design: wave = 64 nodes x 16 feats; thread = 2 nodes (g=lane&31) x 16 f,
//  k-dim split over wave halves (h=lane>>5 owns 32 of 64 k):
//   * acts: global->reg, zero redundancy (16 float4/thread/GEMM).
//   * weights: LDS, stride 68 (16B-aligned -> true ds_read_b128; h-lanes
//     same-bank broadcast = 2-way = free). 4 b128 + 32 FMA per kk.
//   * k-halves combined with ONE shfl_xor(32) per element (select-send);
//     el/er are linear in the split -> partial-scalar reduce via tiny LDS.
//   * bias added once post-combine.
//  k_aggr + CSR build unchanged.
// ---------------------------------------------------------------------------

__global__ void k_zero(int* __restrict__ counts, int N) {
  int i = blockIdx.x * 256 + threadIdx.x;
  if (i < N) counts[i] = 0;
}

__global__ void k_hist(const int* __restrict__ dst, int* __restrict__ counts, int E) {
  int e = blockIdx.x * blockDim.x + threadIdx.x;
  if (e < E) atomicAdd(&counts[dst[e]], 1);
}

__global__ __launch_bounds__(1024) void k_bsum(const int* __restrict__ counts,
                                               int* __restrict__ bsum, int n) {
  __shared__ int wsum[16];
  int tid = threadIdx.x, lane = tid & 63, wid = tid >> 6;
  int i = blockIdx.x * 1024 + tid;
  int v = (i < n) ? counts[i] : 0;
  #pragma unroll
  for (int off = 32; off; off >>= 1) v += __shfl_xor(v, off, 64);
  if (lane == 0) wsum[wid] = v;
  __syncthreads();
  if (wid == 0) {
    int w = (lane < 16) ? wsum[lane] : 0;
    #pragma unroll
    for (int off = 8; off; off >>= 1) w += __shfl_xor(w, off, 64);
    if (lane == 0) bsum[blockIdx.x] = w;
  }
}

__global__ __launch_bounds__(64) void k_bscan(const int* __restrict__ bsum,
                                              int* __restrict__ bofs,
                                              int* __restrict__ row_ptr,
                                              int nb, int n) {
  int lane = threadIdx.x;
  int carry = 0;
  for (int base = 0; base < nb; base += 64) {
    int idx = base + lane;
    int orig = (idx < nb) ? bsum[idx] : 0;
    int inc = orig;
    #pragma unroll
    for (int off = 1; off < 64; off <<= 1) {
      int t = __shfl_up(inc, off, 64);
      if (lane >= off) inc += t;
    }
    if (idx < nb) bofs[idx] = carry + inc - orig;
    carry += __shfl(inc, 63, 64);
  }
  if (lane == 0) row_ptr[n] = carry;
}

__global__ __launch_bounds__(1024) void k_scan3(const int* __restrict__ counts,
                                                const int* __restrict__ bofs,
                                                int* __restrict__ row_ptr,
                                                int* __restrict__ cursor, int n) {
  __shared__ int wsum[16];
  int tid = threadIdx.x, lane = tid & 63, wid = tid >> 6;
  int i = blockIdx.x * 1024 + tid;
  int v = (i < n) ? counts[i] : 0;
  int inc = v;
  #pragma unroll
  for (int off = 1; off < 64; off <<= 1) {
    int t = __shfl_up(inc, off, 64);
    if (lane >= off) inc += t;
  }
  if (lane == 63) wsum[wid] = inc;
  __syncthreads();
  if (wid == 0 && lane < 16) {
    int orig = wsum[lane];
    int w = orig;
    #pragma unroll
    for (int off = 1; off < 16; off <<= 1) {
      int t = __shfl_up(w, off, 64);
      if (lane >= off) w += t;
    }
    wsum[lane] = w - orig;
  }
  __syncthreads();
  int excl = bofs[blockIdx.x] + wsum[wid] + inc - v;
  if (i < n) { row_ptr[i] = excl; cursor[i] = excl; }
}

__global__ void k_scatter(const int* __restrict__ src, const int* __restrict__ dst,
                          int* __restrict__ cursor, int* __restrict__ csr_src, int E) {
  int e = blockIdx.x * blockDim.x + threadIdx.x;
  if (e < E) {
    int pos = atomicAdd(&cursor[dst[e]], 1);
    csr_src[pos] = src[e];
  }
}

// ---- dense-kernel building blocks ----
#define SW_STRIDE 68   // float stride: 16B-aligned rows, conflict-friendly

// stage one 64x64 fp32 row-major matrix into LDS at stride SW_STRIDE
#define STAGE_W(DST, SRC)                                            \
  {                                                                  \
    int k_ = threadIdx.x >> 2, p_ = threadIdx.x & 3;                 \
    const float* s_ = (SRC) + k_ * 64 + p_ * 16;                     \
    float* d_ = (DST) + k_ * SW_STRIDE + p_ * 16;                    \
    _Pragma("unroll")                                                \
    for (int c_ = 0; c_ < 4; c_++)                                   \
      *(float4*)(d_ + c_ * 4) = *(const float4*)(s_ + c_ * 4);       \
  }

#define LOAD16(A, P)                                                 \
  { _Pragma("unroll")                                                \
    for (int c_ = 0; c_ < 4; c_++)                                   \
      *(float4*)&(A)[c_ * 4] = *(const float4*)((P) + c_ * 4); }

// one 16-k round: ACC[2][16] += a0/a1 (acts) x sW rows [KB..KB+15]
#define KROUND(ACC, A0, A1, KB)                                      \
  { _Pragma("unroll")                                                \
    for (int kk_ = 0; kk_ < 16; kk_++) {                             \
      float w_[16];                                                  \
      const float* wr_ = &sW[((KB) + kk_) * SW_STRIDE + f0];         \
      LOAD16(w_, wr_);                                               \
      _Pragma("unroll")                                              \
      for (int j_ = 0; j_ < 16; j_++) {                              \
        ACC[0][j_] = fmaf((A0)[kk_], w_[j_], ACC[0][j_]);            \
        ACC[1][j_] = fmaf((A1)[kk_], w_[j_], ACC[1][j_]);            \
      }                                                              \
    } }

// combine the two k-halves for element j: mine(row h) + partner's(row h)
#define HCOMBINE(ACC, J)                                             \
  (((h == 0) ? ACC[0][J] : ACC[1][J]) +                              \
   __shfl_xor((h == 0) ? ACC[1][J] : ACC[0][J], 32, 64))

// ---- feat = hin @ Wg; el/er (layers 1..3) ----
__global__ __launch_bounds__(256, 4) void k_feat(const float* __restrict__ hin,
                                                 const float* __restrict__ Wg,
                                                 const float* __restrict__ al,
                                                 const float* __restrict__ ar,
                                                 float* __restrict__ feat,
                                                 float* __restrict__ el,
                                                 float* __restrict__ er, int N) {
  __shared__ float sW[64 * SW_STRIDE];
  __shared__ float sEl[512], sEr[512];
  int tid = threadIdx.x, lane = tid & 63, wv = tid >> 6;
  int g = lane & 31, h = lane >> 5;
  int f0 = wv * 16;
  int nb0 = blockIdx.x * 64, nl = N - 1;
  int n0 = nb0 + g * 2;
  const float* p0 = hin + (size_t)min(n0, nl) * 64 + h * 32;
  const float* p1 = hin + (size_t)min(n0 + 1, nl) * 64 + h * 32;
  STAGE_W(sW, Wg);
  __syncthreads();
  float acc[2][16];
  #pragma unroll
  for (int j = 0; j < 16; j++) { acc[0][j] = 0.f; acc[1][j] = 0.f; }
  {
    float a0[16], a1[16], a2[16], a3[16];
    LOAD16(a0, p0); LOAD16(a1, p1);
    LOAD16(a2, p0 + 16); LOAD16(a3, p1 + 16);
    KROUND(acc, a0, a1, h * 32);
    KROUND(acc, a2, a3, h * 32 + 16);
  }
  // el/er: linear in k-split -> per-half scalar partials, no shuffles
  {
    float alv[16], arv[16];
    LOAD16(alv, al + f0); LOAD16(arv, ar + f0);
    float pl0 = 0.f, pl1 = 0.f, pr0 = 0.f, pr1 = 0.f;
    #pragma unroll
    for (int j = 0; j < 16; j++) {
      pl0 = fmaf(acc[0][j], alv[j], pl0);
      pl1 = fmaf(acc[1][j], alv[j], pl1);
      pr0 = fmaf(acc[0][j], arv[j], pr0);
      pr1 = fmaf(acc[1][j], arv[j], pr1);
    }
    sEl[wv * 128 + g * 4 + h]     = pl0;   // local node 2g,   half h
    sEl[wv * 128 + g * 4 + 2 + h] = pl1;   // local node 2g+1, half h
    sEr[wv * 128 + g * 4 + h]     = pr0;
    sEr[wv * 128 + g * 4 + 2 + h] = pr1;
  }
  // combine halves; lane (g,h) owns node 2g+h
  float fullv[16];
  #pragma unroll
  for (int j = 0; j < 16; j++) fullv[j] = HCOMBINE(acc, j);
  int node = nb0 + g * 2 + h;
  if (node < N) {
    float* fp = feat + (size_t)node * 64 + f0;
    #pragma unroll
    for (int c = 0; c < 4; c++)
      *(float4*)(fp + c * 4) =
          make_float4(fullv[c*4], fullv[c*4+1], fullv[c*4+2], fullv[c*4+3]);
  }
  __syncthreads();
  if (tid < 64) {
    int n = nb0 + tid;
    if (n < N) {
      float s = 0.f;
      #pragma unroll
      for (int w2 = 0; w2 < 4; w2++)
        s += sEl[w2 * 128 + tid * 2] + sEl[w2 * 128 + tid * 2 + 1];
      el[n] = s;
    }
  } else if (tid < 128) {
    int t = tid - 64, n = nb0 + t;
    if (n < N) {
      float s = 0.f;
      #pragma unroll
      for (int w2 = 0; w2 < 4; w2++)
        s += sEr[w2 * 128 + t * 2] + sEr[w2 * 128 + t * 2 + 1];
      er[n] = s;
    }
  }
}

// ---- fused: h = tanh(x@We); feat = h@Wg0; el/er. h never hits global ----
__global__ __launch_bounds__(256, 4) void k_embed_feat(
    const float* __restrict__ x, const float* __restrict__ We,
    const float* __restrict__ Wg, const float* __restrict__ al,
    const float* __restrict__ ar, float* __restrict__ feat,
    float* __restrict__ el, float* __restrict__ er, int N) {
  __shared__ float sW[64 * SW_STRIDE];
  __shared__ float sH[64 * SW_STRIDE];
  __shared__ float sEl[512], sEr[512];
  int tid = threadIdx.x, lane = tid & 63, wv = tid >> 6;
  int g = lane & 31, h = lane >> 5;
  int f0 = wv * 16;
  int nb0 = blockIdx.x * 64, nl = N - 1;
  int n0 = nb0 + g * 2;
  const float* x0 = x + (size_t)min(n0, nl) * 128 + h * 32;
  const float* x1 = x + (size_t)min(n0 + 1, nl) * 128 + h * 32;
  float acc[2][16];
  #pragma unroll
  for (int j = 0; j < 16; j++) { acc[0][j] = 0.f; acc[1][j] = 0.f; }
  // GEMM1: x(128k) @ We, two 64-row weight stages
  #pragma unroll
  for (int R = 0; R < 2; R++) {
    if (R) __syncthreads();
    STAGE_W(sW, We + R * 4096);
    __syncthreads();
    const float* q0 = x0 + R * 64;
    const float* q1 = x1 + R * 64;
    float a0[16], a1[16], a2[16], a3[16];
    LOAD16(a0, q0); LOAD16(a1, q1);
    LOAD16(a2, q0 + 16); LOAD16(a3, q1 + 16);
    KROUND(acc, a0, a1, h * 32);
    KROUND(acc, a2, a3, h * 32 + 16);
  }
  __syncthreads();
  STAGE_W(sW, Wg);
  // combine halves -> tanh -> exchange into sH (lane owns node 2g+h)
  {
    int nodeL = g * 2 + h;
    #pragma unroll
    for (int j = 0; j < 16; j++)
      sH[nodeL * SW_STRIDE + f0 + j] = tanhf(HCOMBINE(acc, j));
  }
  __syncthreads();
  // GEMM2: h @ Wg0
  float acc2[2][16];
  #pragma unroll
  for (int j = 0; j < 16; j++) { acc2[0][j] = 0.f; acc2[1][j] = 0.f; }
  {
    const float* r0 = &sH[(g * 2) * SW_STRIDE + h * 32];
    const float* r1 = &sH[(g * 2 + 1) * SW_STRIDE + h * 32];
    float a0[16], a1[16], a2[16], a3[16];
    LOAD16(a0, r0); LOAD16(a1, r1);
    LOAD16(a2, r0 + 16); LOAD16(a3, r1 + 16);
    KROUND(acc2, a0, a1, h * 32);
    KROUND(acc2, a2, a3, h * 32 + 16);
  }
  {
    float alv[16], arv[16];
    LOAD16(alv, al + f0); LOAD16(arv, ar + f0);
    float pl0 = 0.f, pl1 = 0.f, pr0 = 0.f, pr1 = 0.f;
    #pragma unroll
    for (int j = 0; j < 16; j++) {
      pl0 = fmaf(acc2[0][j], alv[j], pl0);
      pl1 = fmaf(acc2[1][j], alv[j], pl1);
      pr0 = fmaf(acc2[0][j], arv[j], pr0);
      pr1 = fmaf(acc2[1][j], arv[j], pr1);
    }
    sEl[wv * 128 + g * 4 + h]     = pl0;
    sEl[wv * 128 + g * 4 + 2 + h] = pl1;
    sEr[wv * 128 + g * 4 + h]     = pr0;
    sEr[wv * 128 + g * 4 + 2 + h] = pr1;
  }
  float fullv[16];
  #pragma unroll
  for (int j = 0; j < 16; j++) fullv[j] = HCOMBINE(acc2, j);
  int node = nb0 + g * 2 + h;
  if (node < N) {
    float* fp = feat + (size_t)node * 64 + f0;
    #pragma unroll
    for (int c = 0; c < 4; c++)
      *(float4*)(fp + c * 4) =
          make_float4(fullv[c*4], fullv[c*4+1], fullv[c*4+2], fullv[c*4+3]);
  }
  __syncthreads();
  if (tid < 64) {
    int n = nb0 + tid;
    if (n < N) {
      float s = 0.f;
      #pragma unroll
      for (int w2 = 0; w2 < 4; w2++)
        s += sEl[w2 * 128 + tid * 2] + sEl[w2 * 128 + tid * 2 + 1];
      el[n] = s;
    }
  } else if (tid < 128) {
    int t = tid - 64, n = nb0 + t;
    if (n < N) {
      float s = 0.f;
      #pragma unroll
      for (int w2 = 0; w2 < 4; w2++)
        s += sEr[w2 * 128 + t * 2] + sEr[w2 * 128 + t * 2 + 1];
      er[n] = s;
    }
  }
}

// ---- edge softmax + aggregate: one wave per dst node, lane = feature ----
__global__ __launch_bounds__(256) void k_aggr(const float* __restrict__ feat,
                                              const float* __restrict__ el,
                                              const float* __restrict__ er,
                                              const int* __restrict__ row_ptr,
                                              const int* __restrict__ csr_src,
                                              unsigned char* __restrict__ mask,
                                              int write_mask, int use_mask,
                                              float* __restrict__ hout, int N) {
  __shared__ __align__(16) int   su[4][64];
  __shared__ __align__(16) float spl[4][64];
  int wv = (int)((blockIdx.x * blockDim.x + threadIdx.x) >> 6);
  int wave = threadIdx.x >> 6, lane = threadIdx.x & 63;
  if (wv >= N) return;
  int beg = row_ptr[wv], end = row_ptr[wv + 1];
  int deg = end - beg;
  float erv = er[wv];
  float acc0 = 0.f, acc1 = 0.f, acc2 = 0.f, acc3 = 0.f;
  if (deg <= 64) {
    int k = beg + lane;
    bool have = (lane < deg);
    int u = have ? csr_src[k] : 0;
    float sc = -INFINITY;
    if (have) {
      float e0 = el[u] + erv;
      sc = (e0 >= 0.f) ? e0 : 0.2f * e0;
      if (use_mask && mask[k] == 0) sc = -1e9f;
    }
    float m = sc;
    #pragma unroll
    for (int off = 32; off; off >>= 1) m = fmaxf(m, __shfl_xor(m, off, 64));
    float pl = have ? expf(sc - m) : 0.f;
    float s = pl;
    #pragma unroll
    for (int off = 32; off; off >>= 1) s += __shfl_xor(s, off, 64);
    pl *= 1.0f / fmaxf(s, 1e-9f);
    if (write_mask && have) mask[k] = (pl >= 0.01f) ? 1 : 0;
    su[wave][lane] = u;
    spl[wave][lane] = pl;
    int dq = (deg + 3) >> 2;
    #pragma unroll 2
    for (int qq = 0; qq < dq; qq++) {
      int4   uu = *(const int4*)&su[wave][qq * 4];
      float4 pp = *(const float4*)&spl[wave][qq * 4];
      acc0 = fmaf(pp.x, feat[(size_t)uu.x * 64 + lane], acc0);
      acc1 = fmaf(pp.y, feat[(size_t)uu.y * 64 + lane], acc1);
      acc2 = fmaf(pp.z, feat[(size_t)uu.z * 64 + lane], acc2);
      acc3 = fmaf(pp.w, feat[(size_t)uu.w * 64 + lane], acc3);
    }
  } else {
    float m = -INFINITY, s = 0.f;
    for (int base = beg; base < end; base += 64) {
      int k = base + lane;
      float sc = -INFINITY;
      if (k < end) {
        int u = csr_src[k];
        float e0 = el[u] + erv;
        sc = (e0 >= 0.f) ? e0 : 0.2f * e0;
        if (use_mask && mask[k] == 0) sc = -1e9f;
      }
      float cm = sc;
      #pragma unroll
      for (int off = 32; off; off >>= 1) cm = fmaxf(cm, __shfl_xor(cm, off, 64));
      float nm = fmaxf(m, cm);
      float t = (k < end) ? expf(sc - nm) : 0.f;
      #pragma unroll
      for (int off = 32; off; off >>= 1) t += __shfl_xor(t, off, 64);
      s = s * expf(m - nm) + t;
      m = nm;
    }
    float inv = 1.0f / fmaxf(s, 1e-9f);
    for (int base = beg; base < end; base += 64) {
      int k = base + lane;
      int u = 0;
      float pl = 0.f;
      if (k < end) {
        u = csr_src[k];
        float e0 = el[u] + erv;
        float sc = (e0 >= 0.f) ? e0 : 0.2f * e0;
        if (use_mask && mask[k] == 0) sc = -1e9f;
        pl = expf(sc - m) * inv;
        if (write_mask) mask[k] = (pl >= 0.01f) ? 1 : 0;
      }
      su[wave][lane] = u;
      spl[wave][lane] = pl;
      int cnt = min(64, end - base);
      int dq = (cnt + 3) >> 2;
      for (int qq = 0; qq < dq; qq++) {
        int4   uu = *(const int4*)&su[wave][qq * 4];
        float4 pp = *(const float4*)&spl[wave][qq * 4];
        acc0 = fmaf(pp.x, feat[(size_t)uu.x * 64 + lane], acc0);
        acc1 = fmaf(pp.y, feat[(size_t)uu.y * 64 + lane], acc1);
        acc2 = fmaf(pp.z, feat[(size_t)uu.z * 64 + lane], acc2);
        acc3 = fmaf(pp.w, feat[(size_t)uu.w * 64 + lane], acc3);
      }
    }
  }
  float acc = (acc0 + acc1) + (acc2 + acc3);
  hout[(size_t)wv * 64 + lane] = (acc > 0.f) ? acc : expm1f(acc);
}

// ---- fused MLP head ----
__global__ __launch_bounds__(256, 4) void k_mlp(const float* __restrict__ o0,
                                                const float* __restrict__ o1,
                                                const float* __restrict__ o2,
                                                const float* __restrict__ o3,
                                                const float* __restrict__ W0,
                                                const float* __restrict__ b0,
                                                const float* __restrict__ W1,
                                                const float* __restrict__ b1,
                                                const float* __restrict__ W2,
                                                const float* __restrict__ b2,
                                                float* __restrict__ out, int N) {
  __shared__ float sW[64 * SW_STRIDE];
  __shared__ float sH[64 * SW_STRIDE];
  __shared__ float sR[256];
  int tid = threadIdx.x, lane = tid & 63, wv = tid >> 6;
  int g = lane & 31, h = lane >> 5;
  int f0 = wv * 16;
  int nb0 = blockIdx.x * 64, nl = N - 1;
  int n0 = nb0 + g * 2;
  float acc[2][16];
  #pragma unroll
  for (int j = 0; j < 16; j++) { acc[0][j] = 0.f; acc[1][j] = 0.f; }
  const float* segs[4] = {o0, o1, o2, o3};
  #pragma unroll
  for (int s = 0; s < 4; s++) {
    if (s) __syncthreads();
    STAGE_W(sW, W0 + s * 4096);
    __syncthreads();
    const float* q0 = segs[s] + (size_t)min(n0, nl) * 64 + h * 32;
    const float* q1 = segs[s] + (size_t)min(n0 + 1, nl) * 64 + h * 32;
    float a0[16], a1[16], a2[16], a3[16];
    LOAD16(a0, q0); LOAD16(a1, q1);
    LOAD16(a2, q0 + 16); LOAD16(a3, q1 + 16);
    KROUND(acc, a0, a1, h * 32);
    KROUND(acc, a2, a3, h * 32 + 16);
  }
  __syncthreads();
  STAGE_W(sW, W1);
  // combine halves + bias + relu -> exchange into sH
  {
    float b0v[16];
    LOAD16(b0v, b0 + f0);
    int nodeL = g * 2 + h;
    #pragma unroll
    for (int j = 0; j < 16; j++) {
      float z = HCOMBINE(acc, j) + b0v[j];
      sH[nodeL * SW_STRIDE + f0 + j] = (z > 0.f) ? z : 0.f;
    }
  }
  __syncthreads();
  // L1 GEMM from sH
  float acc2[2][16];
  #pragma unroll
  for (int j = 0; j < 16; j++) { acc2[0][j] = 0.f; acc2[1][j] = 0.f; }
  {
    const float* r0 = &sH[(g * 2) * SW_STRIDE + h * 32];
    const float* r1 = &sH[(g * 2 + 1) * SW_STRIDE + h * 32];
    float a0[16], a1[16], a2[16], a3[16];
    LOAD16(a0, r0); LOAD16(a1, r1);
    LOAD16(a2, r0 + 16); LOAD16(a3, r1 + 16);
    KROUND(acc2, a0, a1, h * 32);
    KROUND(acc2, a2, a3, h * 32 + 16);
  }
  // L2: combine + b1 + relu + dot W2
  {
    float b1v[16], w2v[16];
    LOAD16(b1v, b1 + f0); LOAD16(w2v, W2 + f0);
    float rp = 0.f;
    #pragma unroll
    for (int j = 0; j < 16; j++) {
      float z = HCOMBINE(acc2, j) + b1v[j];
      z = (z > 0.f) ? z : 0.f;
      rp = fmaf(z, w2v[j], rp);
    }
    sR[wv * 64 + g * 2 + h] = rp;
  }
  __syncthreads();
  if (tid < 64) {
    int n = nb0 + tid;
    if (n < N) {
      float o = (sR[tid] + sR[64 + tid]) + (sR[128 + tid] + sR[192 + tid]) + b2[0];
      out[n] = (o > 0.f) ? o : 0.f;
    }
  }
}

extern "C" void kernel_launch(void* const* d_in, const int* in_sizes, int n_in,
                              void* d_out, int out_size, void* d_ws, size_t ws_size,
                              hipStream_t stream) {
  const float* x       = (const float*)d_in[0];
  const int*   esrc    = (const int*)d_in[1];
  const int*   edst    = (const int*)d_in[2];
  const float* W_embed = (const float*)d_in[3];
  const float* W_gat   = (const float*)d_in[4];
  const float* a_l     = (const float*)d_in[5];
  const float* a_r     = (const float*)d_in[6];
  const float* W0      = (const float*)d_in[7];
  const float* b0      = (const float*)d_in[8];
  const float* W1      = (const float*)d_in[9];
  const float* b1      = (const float*)d_in[10];
  const float* W2      = (const float*)d_in[11];
  const float* b2      = (const float*)d_in[12];
  float* out = (float*)d_out;
  const int N = in_sizes[0] / 128;
  const int E = in_sizes[1];

  char* p = (char*)d_ws;
  auto alloc = [&](size_t bytes) -> char* {
    char* r = p;
    p += (bytes + 255) & ~(size_t)255;
    return r;
  };
  float* out0 = (float*)alloc((size_t)N * 64 * 4);
  float* out1 = (float*)alloc((size_t)N * 64 * 4);
  float* out2 = (float*)alloc((size_t)N * 64 * 4);
  float* out3 = (float*)alloc((size_t)N * 64 * 4);
  float* feat = (float*)alloc((size_t)N * 64 * 4);
  float* el   = (float*)alloc((size_t)N * 4);
  float* er   = (float*)alloc((size_t)N * 4);
  int* counts  = (int*)alloc((size_t)N * 4);
  int* row_ptr = (int*)alloc((size_t)(N + 1) * 4);
  int* cursor  = (int*)alloc((size_t)N * 4);
  int* csr_src = (int*)alloc((size_t)E * 4);
  unsigned char* mask = (unsigned char*)alloc((size_t)E);
  int nb = (N + 1023) / 1024;
  int* bsum = (int*)alloc((size_t)nb * 4);
  int* bofs = (int*)alloc((size_t)nb * 4);

  // --- CSR build (dst-sorted) ---
  k_zero<<<(N + 255) / 256, 256, 0, stream>>>(counts, N);
  k_hist<<<(E + 255) / 256, 256, 0, stream>>>(edst, counts, E);
  k_bsum<<<nb, 1024, 0, stream>>>(counts, bsum, N);
  k_bscan<<<1, 64, 0, stream>>>(bsum, bofs, row_ptr, nb, N);
  k_scan3<<<nb, 1024, 0, stream>>>(counts, bofs, row_ptr, cursor, N);
  k_scatter<<<(E + 255) / 256, 256, 0, stream>>>(esrc, edst, cursor, csr_src, E);

  // --- dense grid: 64 nodes per 256-thread block ---
  int dgb = (N + 63) / 64;

  // --- layer 0: fused embed + feat ---
  k_embed_feat<<<dgb, 256, 0, stream>>>(x, W_embed, W_gat,
                                        a_l, a_r, feat, el, er, N);
  float* outs[4] = {out0, out1, out2, out3};
  k_aggr<<<(N + 3) / 4, 256, 0, stream>>>(feat, el, er, row_ptr, csr_src, mask,
                                          1, 0, out0, N);

  // --- layers 1..3 ---
  for (int l = 1; l < 4; l++) {
    k_feat<<<dgb, 256, 0, stream>>>(outs[l - 1], W_gat + (size_t)l * 4096,
                                    a_l + (size_t)l * 64, a_r + (size_t)l * 64,
                                    feat, el, er, N);
    k_aggr<<<(N + 3) / 4, 256, 0, stream>>>(feat, el, er, row_ptr, csr_src, mask,
                                            0, 1, outs[l], N);
  }

  // --- MLP head ---
  k_mlp<<<dgb, 256, 0, stream>>>(out0, out1, out2, out3, W0, b0,
                                 W1, b1, W2, b2, out, N);
}

// Round 5
// 550.408 us; speedup vs baseline: 1.0369x; 1.0369x over previous
//
#include <hip/hip_runtime.h>
#include <math.h>

// ---------------------------------------------------------------------------
// SNAT3: 4-layer GAT GNN. N=50000, E=800000, HID=64, fp32.
// R12 = R11 k-split structure minus the register spill.
//  R11 post-mortem: WRITE_SIZE 202MB / FETCH 190MB on k_embed_feat = scratch
//  spill traffic (a0..a3[16]+acc+w ~130 VGPR vs launch_bounds(256,4) cap 128;
//  compiler reported 64 VGPR + spilled). Fixes:
//   * acts STREAMED one float4/node per 4-k chunk (live set ~90 VGPR).
//   * __launch_bounds__(256,3): cap ~170 VGPR; grid is 3 blocks/CU anyway.
//   * node ownership (g, g+32): coalesced feat writes, clean banks.
//   * h-exchange TRANSPOSED sHT[f][node] stride 65: writes (f+n)%32 2-way,
//     reads (kk+g)%32 2-way -> all free (R11 had 8-way on the exchange).
//  Weights stay in LDS stride 68 (uniform ds_read_b128 broadcast).
//  k-halves combined with one select-send shfl_xor(32) per element.
//  k_aggr + CSR build unchanged (R8).
// ---------------------------------------------------------------------------

__global__ void k_zero(int* __restrict__ counts, int N) {
  int i = blockIdx.x * 256 + threadIdx.x;
  if (i < N) counts[i] = 0;
}

__global__ void k_hist(const int* __restrict__ dst, int* __restrict__ counts, int E) {
  int e = blockIdx.x * blockDim.x + threadIdx.x;
  if (e < E) atomicAdd(&counts[dst[e]], 1);
}

__global__ __launch_bounds__(1024) void k_bsum(const int* __restrict__ counts,
                                               int* __restrict__ bsum, int n) {
  __shared__ int wsum[16];
  int tid = threadIdx.x, lane = tid & 63, wid = tid >> 6;
  int i = blockIdx.x * 1024 + tid;
  int v = (i < n) ? counts[i] : 0;
  #pragma unroll
  for (int off = 32; off; off >>= 1) v += __shfl_xor(v, off, 64);
  if (lane == 0) wsum[wid] = v;
  __syncthreads();
  if (wid == 0) {
    int w = (lane < 16) ? wsum[lane] : 0;
    #pragma unroll
    for (int off = 8; off; off >>= 1) w += __shfl_xor(w, off, 64);
    if (lane == 0) bsum[blockIdx.x] = w;
  }
}

__global__ __launch_bounds__(64) void k_bscan(const int* __restrict__ bsum,
                                              int* __restrict__ bofs,
                                              int* __restrict__ row_ptr,
                                              int nb, int n) {
  int lane = threadIdx.x;
  int carry = 0;
  for (int base = 0; base < nb; base += 64) {
    int idx = base + lane;
    int orig = (idx < nb) ? bsum[idx] : 0;
    int inc = orig;
    #pragma unroll
    for (int off = 1; off < 64; off <<= 1) {
      int t = __shfl_up(inc, off, 64);
      if (lane >= off) inc += t;
    }
    if (idx < nb) bofs[idx] = carry + inc - orig;
    carry += __shfl(inc, 63, 64);
  }
  if (lane == 0) row_ptr[n] = carry;
}

__global__ __launch_bounds__(1024) void k_scan3(const int* __restrict__ counts,
                                                const int* __restrict__ bofs,
                                                int* __restrict__ row_ptr,
                                                int* __restrict__ cursor, int n) {
  __shared__ int wsum[16];
  int tid = threadIdx.x, lane = tid & 63, wid = tid >> 6;
  int i = blockIdx.x * 1024 + tid;
  int v = (i < n) ? counts[i] : 0;
  int inc = v;
  #pragma unroll
  for (int off = 1; off < 64; off <<= 1) {
    int t = __shfl_up(inc, off, 64);
    if (lane >= off) inc += t;
  }
  if (lane == 63) wsum[wid] = inc;
  __syncthreads();
  if (wid == 0 && lane < 16) {
    int orig = wsum[lane];
    int w = orig;
    #pragma unroll
    for (int off = 1; off < 16; off <<= 1) {
      int t = __shfl_up(w, off, 64);
      if (lane >= off) w += t;
    }
    wsum[lane] = w - orig;
  }
  __syncthreads();
  int excl = bofs[blockIdx.x] + wsum[wid] + inc - v;
  if (i < n) { row_ptr[i] = excl; cursor[i] = excl; }
}

__global__ void k_scatter(const int* __restrict__ src, const int* __restrict__ dst,
                          int* __restrict__ cursor, int* __restrict__ csr_src, int E) {
  int e = blockIdx.x * blockDim.x + threadIdx.x;
  if (e < E) {
    int pos = atomicAdd(&cursor[dst[e]], 1);
    csr_src[pos] = src[e];
  }
}

// ---- dense building blocks ----
#define SW_STRIDE 68   // 272B rows: 16B-aligned, uniform b128 broadcast
#define SH_STRIDE 65   // transposed exchange [f][node]: banks (f+n)%32

// stage one 64x64 fp32 row-major matrix into LDS at stride SW_STRIDE
#define STAGE_W(DST, SRC)                                            \
  {                                                                  \
    int k_ = threadIdx.x >> 2, p_ = threadIdx.x & 3;                 \
    const float* s_ = (SRC) + k_ * 64 + p_ * 16;                     \
    float* d_ = (DST) + k_ * SW_STRIDE + p_ * 16;                    \
    _Pragma("unroll")                                                \
    for (int c_ = 0; c_ < 4; c_++)                                   \
      *(float4*)(d_ + c_ * 4) = *(const float4*)(s_ + c_ * 4);       \
  }

#define LOAD16(A, P)                                                 \
  { _Pragma("unroll")                                                \
    for (int c_ = 0; c_ < 4; c_++)                                   \
      *(float4*)&(A)[c_ * 4] = *(const float4*)((P) + c_ * 4); }

// streamed 32-k GEMM: ACC[2][16] += acts(P0,P1)[0..31] x sW rows KB..KB+31
// acts loaded one float4 per node per 4-k chunk -> no spill
#define GEMM32(ACC, P0, P1, KB)                                      \
  { _Pragma("unroll")                                                \
    for (int kq_ = 0; kq_ < 8; kq_++) {                              \
      float4 a0_ = *(const float4*)((P0) + kq_ * 4);                 \
      float4 a1_ = *(const float4*)((P1) + kq_ * 4);                 \
      float aa0_[4] = {a0_.x, a0_.y, a0_.z, a0_.w};                  \
      float aa1_[4] = {a1_.x, a1_.y, a1_.z, a1_.w};                  \
      _Pragma("unroll")                                              \
      for (int kk_ = 0; kk_ < 4; kk_++) {                            \
        float w_[16];                                                \
        const float* wr_ = &sW[((KB) + kq_ * 4 + kk_) * SW_STRIDE + f0]; \
        LOAD16(w_, wr_);                                             \
        _Pragma("unroll")                                            \
        for (int j_ = 0; j_ < 16; j_++) {                            \
          ACC[0][j_] = fmaf(aa0_[kk_], w_[j_], ACC[0][j_]);          \
          ACC[1][j_] = fmaf(aa1_[kk_], w_[j_], ACC[1][j_]);          \
        }                                                            \
      }                                                              \
    } }

// 32-k GEMM from transposed LDS acts sHT[f][node] (cols N0, N0+32)
#define GEMM32_LDS(ACC, N0, KB)                                      \
  { _Pragma("unroll")                                                \
    for (int kk_ = 0; kk_ < 32; kk_++) {                             \
      float w_[16];                                                  \
      const float* wr_ = &sW[((KB) + kk_) * SW_STRIDE + f0];         \
      LOAD16(w_, wr_);                                               \
      float h0_ = sHT[((KB) + kk_) * SH_STRIDE + (N0)];              \
      float h1_ = sHT[((KB) + kk_) * SH_STRIDE + (N0) + 32];         \
      _Pragma("unroll")                                              \
      for (int j_ = 0; j_ < 16; j_++) {                              \
        ACC[0][j_] = fmaf(h0_, w_[j_], ACC[0][j_]);                  \
        ACC[1][j_] = fmaf(h1_, w_[j_], ACC[1][j_]);                  \
      }                                                              \
    } }

// combine halves; lane (g,h) keeps node g+32h: keep ACC[h], recv partner's
#define HCOMBINE(ACC, J)                                             \
  (((h) ? ACC[1][J] : ACC[0][J]) +                                   \
   __shfl_xor((h) ? ACC[0][J] : ACC[1][J], 32, 64))

// ---- feat = hin @ Wg; el/er (layers 1..3) ----
__global__ __launch_bounds__(256, 3) void k_feat(const float* __restrict__ hin,
                                                 const float* __restrict__ Wg,
                                                 const float* __restrict__ al,
                                                 const float* __restrict__ ar,
                                                 float* __restrict__ feat,
                                                 float* __restrict__ el,
                                                 float* __restrict__ er, int N) {
  __shared__ float sW[64 * SW_STRIDE];
  __shared__ float sEl[512], sEr[512];
  int tid = threadIdx.x, lane = tid & 63, wv = tid >> 6;
  int g = lane & 31, h = lane >> 5;
  int f0 = wv * 16;
  int nb0 = blockIdx.x * 64, nl = N - 1;
  int nA = nb0 + g, nB = nb0 + g + 32;
  const float* p0 = hin + (size_t)min(nA, nl) * 64 + h * 32;
  const float* p1 = hin + (size_t)min(nB, nl) * 64 + h * 32;
  STAGE_W(sW, Wg);
  __syncthreads();
  float acc[2][16];
  #pragma unroll
  for (int j = 0; j < 16; j++) { acc[0][j] = 0.f; acc[1][j] = 0.f; }
  GEMM32(acc, p0, p1, h * 32);
  // el/er: linear in k-split -> per-half scalar partials
  {
    float alv[16], arv[16];
    LOAD16(alv, al + f0); LOAD16(arv, ar + f0);
    float pl0 = 0.f, pl1 = 0.f, pr0 = 0.f, pr1 = 0.f;
    #pragma unroll
    for (int j = 0; j < 16; j++) {
      pl0 = fmaf(acc[0][j], alv[j], pl0);
      pl1 = fmaf(acc[1][j], alv[j], pl1);
      pr0 = fmaf(acc[0][j], arv[j], pr0);
      pr1 = fmaf(acc[1][j], arv[j], pr1);
    }
    sEl[wv * 128 + g * 2 + h]        = pl0;   // node g
    sEl[wv * 128 + (g + 32) * 2 + h] = pl1;   // node g+32
    sEr[wv * 128 + g * 2 + h]        = pr0;
    sEr[wv * 128 + (g + 32) * 2 + h] = pr1;
  }
  float fullv[16];
  #pragma unroll
  for (int j = 0; j < 16; j++) fullv[j] = HCOMBINE(acc, j);
  int node = nb0 + g + 32 * h;
  if (node < N) {
    float* fp = feat + (size_t)node * 64 + f0;
    #pragma unroll
    for (int c = 0; c < 4; c++)
      *(float4*)(fp + c * 4) =
          make_float4(fullv[c*4], fullv[c*4+1], fullv[c*4+2], fullv[c*4+3]);
  }
  __syncthreads();
  if (tid < 64) {
    int n = nb0 + tid;
    if (n < N) {
      float s = 0.f;
      #pragma unroll
      for (int w2 = 0; w2 < 4; w2++)
        s += sEl[w2 * 128 + tid * 2] + sEl[w2 * 128 + tid * 2 + 1];
      el[n] = s;
    }
  } else if (tid < 128) {
    int t = tid - 64, n = nb0 + t;
    if (n < N) {
      float s = 0.f;
      #pragma unroll
      for (int w2 = 0; w2 < 4; w2++)
        s += sEr[w2 * 128 + t * 2] + sEr[w2 * 128 + t * 2 + 1];
      er[n] = s;
    }
  }
}

// ---- fused: h = tanh(x@We); feat = h@Wg0; el/er. h never hits global ----
__global__ __launch_bounds__(256, 3) void k_embed_feat(
    const float* __restrict__ x, const float* __restrict__ We,
    const float* __restrict__ Wg, const float* __restrict__ al,
    const float* __restrict__ ar, float* __restrict__ feat,
    float* __restrict__ el, float* __restrict__ er, int N) {
  __shared__ float sW[64 * SW_STRIDE];
  __shared__ float sHT[64 * SH_STRIDE];   // transposed [f][node]
  __shared__ float sEl[512], sEr[512];
  int tid = threadIdx.x, lane = tid & 63, wv = tid >> 6;
  int g = lane & 31, h = lane >> 5;
  int f0 = wv * 16;
  int nb0 = blockIdx.x * 64, nl = N - 1;
  int nA = nb0 + g, nB = nb0 + g + 32;
  const float* x0 = x + (size_t)min(nA, nl) * 128 + h * 32;
  const float* x1 = x + (size_t)min(nB, nl) * 128 + h * 32;
  float acc[2][16];
  #pragma unroll
  for (int j = 0; j < 16; j++) { acc[0][j] = 0.f; acc[1][j] = 0.f; }
  // GEMM1: x(128k) @ We in two 64-row stages
  #pragma unroll
  for (int R = 0; R < 2; R++) {
    if (R) __syncthreads();
    STAGE_W(sW, We + R * 4096);
    __syncthreads();
    GEMM32(acc, x0 + R * 64, x1 + R * 64, h * 32);
  }
  __syncthreads();
  STAGE_W(sW, Wg);
  // combine -> tanh -> transposed exchange (lane owns node g+32h)
  {
    int nodeL = g + 32 * h;
    #pragma unroll
    for (int j = 0; j < 16; j++)
      sHT[(f0 + j) * SH_STRIDE + nodeL] = tanhf(HCOMBINE(acc, j));
  }
  __syncthreads();
  // GEMM2: h @ Wg0 from sHT
  float acc2[2][16];
  #pragma unroll
  for (int j = 0; j < 16; j++) { acc2[0][j] = 0.f; acc2[1][j] = 0.f; }
  GEMM32_LDS(acc2, g, h * 32);
  {
    float alv[16], arv[16];
    LOAD16(alv, al + f0); LOAD16(arv, ar + f0);
    float pl0 = 0.f, pl1 = 0.f, pr0 = 0.f, pr1 = 0.f;
    #pragma unroll
    for (int j = 0; j < 16; j++) {
      pl0 = fmaf(acc2[0][j], alv[j], pl0);
      pl1 = fmaf(acc2[1][j], alv[j], pl1);
      pr0 = fmaf(acc2[0][j], arv[j], pr0);
      pr1 = fmaf(acc2[1][j], arv[j], pr1);
    }
    sEl[wv * 128 + g * 2 + h]        = pl0;
    sEl[wv * 128 + (g + 32) * 2 + h] = pl1;
    sEr[wv * 128 + g * 2 + h]        = pr0;
    sEr[wv * 128 + (g + 32) * 2 + h] = pr1;
  }
  float fullv[16];
  #pragma unroll
  for (int j = 0; j < 16; j++) fullv[j] = HCOMBINE(acc2, j);
  int node = nb0 + g + 32 * h;
  if (node < N) {
    float* fp = feat + (size_t)node * 64 + f0;
    #pragma unroll
    for (int c = 0; c < 4; c++)
      *(float4*)(fp + c * 4) =
          make_float4(fullv[c*4], fullv[c*4+1], fullv[c*4+2], fullv[c*4+3]);
  }
  __syncthreads();
  if (tid < 64) {
    int n = nb0 + tid;
    if (n < N) {
      float s = 0.f;
      #pragma unroll
      for (int w2 = 0; w2 < 4; w2++)
        s += sEl[w2 * 128 + tid * 2] + sEl[w2 * 128 + tid * 2 + 1];
      el[n] = s;
    }
  } else if (tid < 128) {
    int t = tid - 64, n = nb0 + t;
    if (n < N) {
      float s = 0.f;
      #pragma unroll
      for (int w2 = 0; w2 < 4; w2++)
        s += sEr[w2 * 128 + t * 2] + sEr[w2 * 128 + t * 2 + 1];
      er[n] = s;
    }
  }
}

// ---- edge softmax + aggregate: one wave per dst node, lane = feature ----
__global__ __launch_bounds__(256) void k_aggr(const float* __restrict__ feat,
                                              const float* __restrict__ el,
                                              const float* __restrict__ er,
                                              const int* __restrict__ row_ptr,
                                              const int* __restrict__ csr_src,
                                              unsigned char* __restrict__ mask,
                                              int write_mask, int use_mask,
                                              float* __restrict__ hout, int N) {
  __shared__ __align__(16) int   su[4][64];
  __shared__ __align__(16) float spl[4][64];
  int wv = (int)((blockIdx.x * blockDim.x + threadIdx.x) >> 6);
  int wave = threadIdx.x >> 6, lane = threadIdx.x & 63;
  if (wv >= N) return;
  int beg = row_ptr[wv], end = row_ptr[wv + 1];
  int deg = end - beg;
  float erv = er[wv];
  float acc0 = 0.f, acc1 = 0.f, acc2 = 0.f, acc3 = 0.f;
  if (deg <= 64) {
    int k = beg + lane;
    bool have = (lane < deg);
    int u = have ? csr_src[k] : 0;
    float sc = -INFINITY;
    if (have) {
      float e0 = el[u] + erv;
      sc = (e0 >= 0.f) ? e0 : 0.2f * e0;
      if (use_mask && mask[k] == 0) sc = -1e9f;
    }
    float m = sc;
    #pragma unroll
    for (int off = 32; off; off >>= 1) m = fmaxf(m, __shfl_xor(m, off, 64));
    float pl = have ? expf(sc - m) : 0.f;
    float s = pl;
    #pragma unroll
    for (int off = 32; off; off >>= 1) s += __shfl_xor(s, off, 64);
    pl *= 1.0f / fmaxf(s, 1e-9f);
    if (write_mask && have) mask[k] = (pl >= 0.01f) ? 1 : 0;
    su[wave][lane] = u;
    spl[wave][lane] = pl;
    int dq = (deg + 3) >> 2;
    #pragma unroll 2
    for (int qq = 0; qq < dq; qq++) {
      int4   uu = *(const int4*)&su[wave][qq * 4];
      float4 pp = *(const float4*)&spl[wave][qq * 4];
      acc0 = fmaf(pp.x, feat[(size_t)uu.x * 64 + lane], acc0);
      acc1 = fmaf(pp.y, feat[(size_t)uu.y * 64 + lane], acc1);
      acc2 = fmaf(pp.z, feat[(size_t)uu.z * 64 + lane], acc2);
      acc3 = fmaf(pp.w, feat[(size_t)uu.w * 64 + lane], acc3);
    }
  } else {
    float m = -INFINITY, s = 0.f;
    for (int base = beg; base < end; base += 64) {
      int k = base + lane;
      float sc = -INFINITY;
      if (k < end) {
        int u = csr_src[k];
        float e0 = el[u] + erv;
        sc = (e0 >= 0.f) ? e0 : 0.2f * e0;
        if (use_mask && mask[k] == 0) sc = -1e9f;
      }
      float cm = sc;
      #pragma unroll
      for (int off = 32; off; off >>= 1) cm = fmaxf(cm, __shfl_xor(cm, off, 64));
      float nm = fmaxf(m, cm);
      float t = (k < end) ? expf(sc - nm) : 0.f;
      #pragma unroll
      for (int off = 32; off; off >>= 1) t += __shfl_xor(t, off, 64);
      s = s * expf(m - nm) + t;
      m = nm;
    }
    float inv = 1.0f / fmaxf(s, 1e-9f);
    for (int base = beg; base < end; base += 64) {
      int k = base + lane;
      int u = 0;
      float pl = 0.f;
      if (k < end) {
        u = csr_src[k];
        float e0 = el[u] + erv;
        float sc = (e0 >= 0.f) ? e0 : 0.2f * e0;
        if (use_mask && mask[k] == 0) sc = -1e9f;
        pl = expf(sc - m) * inv;
        if (write_mask) mask[k] = (pl >= 0.01f) ? 1 : 0;
      }
      su[wave][lane] = u;
      spl[wave][lane] = pl;
      int cnt = min(64, end - base);
      int dq = (cnt + 3) >> 2;
      for (int qq = 0; qq < dq; qq++) {
        int4   uu = *(const int4*)&su[wave][qq * 4];
        float4 pp = *(const float4*)&spl[wave][qq * 4];
        acc0 = fmaf(pp.x, feat[(size_t)uu.x * 64 + lane], acc0);
        acc1 = fmaf(pp.y, feat[(size_t)uu.y * 64 + lane], acc1);
        acc2 = fmaf(pp.z, feat[(size_t)uu.z * 64 + lane], acc2);
        acc3 = fmaf(pp.w, feat[(size_t)uu.w * 64 + lane], acc3);
      }
    }
  }
  float acc = (acc0 + acc1) + (acc2 + acc3);
  hout[(size_t)wv * 64 + lane] = (acc > 0.f) ? acc : expm1f(acc);
}

// ---- fused MLP head ----
__global__ __launch_bounds__(256, 3) void k_mlp(const float* __restrict__ o0,
                                                const float* __restrict__ o1,
                                                const float* __restrict__ o2,
                                                const float* __restrict__ o3,
                                                const float* __restrict__ W0,
                                                const float* __restrict__ b0,
                                                const float* __restrict__ W1,
                                                const float* __restrict__ b1,
                                                const float* __restrict__ W2,
                                                const float* __restrict__ b2,
                                                float* __restrict__ out, int N) {
  __shared__ float sW[64 * SW_STRIDE];
  __shared__ float sHT[64 * SH_STRIDE];
  __shared__ float sR[256];
  int tid = threadIdx.x, lane = tid & 63, wv = tid >> 6;
  int g = lane & 31, h = lane >> 5;
  int f0 = wv * 16;
  int nb0 = blockIdx.x * 64, nl = N - 1;
  int nA = nb0 + g, nB = nb0 + g + 32;
  float acc[2][16];
  #pragma unroll
  for (int j = 0; j < 16; j++) { acc[0][j] = 0.f; acc[1][j] = 0.f; }
  const float* segs[4] = {o0, o1, o2, o3};
  #pragma unroll
  for (int s = 0; s < 4; s++) {
    if (s) __syncthreads();
    STAGE_W(sW, W0 + s * 4096);
    __syncthreads();
    const float* p0 = segs[s] + (size_t)min(nA, nl) * 64 + h * 32;
    const float* p1 = segs[s] + (size_t)min(nB, nl) * 64 + h * 32;
    GEMM32(acc, p0, p1, h * 32);
  }
  __syncthreads();
  STAGE_W(sW, W1);
  // combine + b0 + relu -> transposed exchange
  {
    float b0v[16];
    LOAD16(b0v, b0 + f0);
    int nodeL = g + 32 * h;
    #pragma unroll
    for (int j = 0; j < 16; j++) {
      float z = HCOMBINE(acc, j) + b0v[j];
      sHT[(f0 + j) * SH_STRIDE + nodeL] = (z > 0.f) ? z : 0.f;
    }
  }
  __syncthreads();
  // L1 GEMM from sHT
  float acc2[2][16];
  #pragma unroll
  for (int j = 0; j < 16; j++) { acc2[0][j] = 0.f; acc2[1][j] = 0.f; }
  GEMM32_LDS(acc2, g, h * 32);
  // L2: combine + b1 + relu + dot W2 (for this lane's node g+32h)
  {
    float b1v[16], w2v[16];
    LOAD16(b1v, b1 + f0); LOAD16(w2v, W2 + f0);
    float rp = 0.f;
    #pragma unroll
    for (int j = 0; j < 16; j++) {
      float z = HCOMBINE(acc2, j) + b1v[j];
      z = (z > 0.f) ? z : 0.f;
      rp = fmaf(z, w2v[j], rp);
    }
    sR[wv * 64 + g + 32 * h] = rp;
  }
  __syncthreads();
  if (tid < 64) {
    int n = nb0 + tid;
    if (n < N) {
      float o = (sR[tid] + sR[64 + tid]) + (sR[128 + tid] + sR[192 + tid]) + b2[0];
      out[n] = (o > 0.f) ? o : 0.f;
    }
  }
}

extern "C" void kernel_launch(void* const* d_in, const int* in_sizes, int n_in,
                              void* d_out, int out_size, void* d_ws, size_t ws_size,
                              hipStream_t stream) {
  const float* x       = (const float*)d_in[0];
  const int*   esrc    = (const int*)d_in[1];
  const int*   edst    = (const int*)d_in[2];
  const float* W_embed = (const float*)d_in[3];
  const float* W_gat   = (const float*)d_in[4];
  const float* a_l     = (const float*)d_in[5];
  const float* a_r     = (const float*)d_in[6];
  const float* W0      = (const float*)d_in[7];
  const float* b0      = (const float*)d_in[8];
  const float* W1      = (const float*)d_in[9];
  const float* b1      = (const float*)d_in[10];
  const float* W2      = (const float*)d_in[11];
  const float* b2      = (const float*)d_in[12];
  float* out = (float*)d_out;
  const int N = in_sizes[0] / 128;
  const int E = in_sizes[1];

  char* p = (char*)d_ws;
  auto alloc = [&](size_t bytes) -> char* {
    char* r = p;
    p += (bytes + 255) & ~(size_t)255;
    return r;
  };
  float* out0 = (float*)alloc((size_t)N * 64 * 4);
  float* out1 = (float*)alloc((size_t)N * 64 * 4);
  float* out2 = (float*)alloc((size_t)N * 64 * 4);
  float* out3 = (float*)alloc((size_t)N * 64 * 4);
  float* feat = (float*)alloc((size_t)N * 64 * 4);
  float* el   = (float*)alloc((size_t)N * 4);
  float* er   = (float*)alloc((size_t)N * 4);
  int* counts  = (int*)alloc((size_t)N * 4);
  int* row_ptr = (int*)alloc((size_t)(N + 1) * 4);
  int* cursor  = (int*)alloc((size_t)N * 4);
  int* csr_src = (int*)alloc((size_t)E * 4);
  unsigned char* mask = (unsigned char*)alloc((size_t)E);
  int nb = (N + 1023) / 1024;
  int* bsum = (int*)alloc((size_t)nb * 4);
  int* bofs = (int*)alloc((size_t)nb * 4);

  // --- CSR build (dst-sorted) ---
  k_zero<<<(N + 255) / 256, 256, 0, stream>>>(counts, N);
  k_hist<<<(E + 255) / 256, 256, 0, stream>>>(edst, counts, E);
  k_bsum<<<nb, 1024, 0, stream>>>(counts, bsum, N);
  k_bscan<<<1, 64, 0, stream>>>(bsum, bofs, row_ptr, nb, N);
  k_scan3<<<nb, 1024, 0, stream>>>(counts, bofs, row_ptr, cursor, N);
  k_scatter<<<(E + 255) / 256, 256, 0, stream>>>(esrc, edst, cursor, csr_src, E);

  // --- dense grid: 64 nodes per 256-thread block ---
  int dgb = (N + 63) / 64;

  // --- layer 0: fused embed + feat ---
  k_embed_feat<<<dgb, 256, 0, stream>>>(x, W_embed, W_gat,
                                        a_l, a_r, feat, el, er, N);
  float* outs[4] = {out0, out1, out2, out3};
  k_aggr<<<(N + 3) / 4, 256, 0, stream>>>(feat, el, er, row_ptr, csr_src, mask,
                                          1, 0, out0, N);

  // --- layers 1..3 ---
  for (int l = 1; l < 4; l++) {
    k_feat<<<dgb, 256, 0, stream>>>(outs[l - 1], W_gat + (size_t)l * 4096,
                                    a_l + (size_t)l * 64, a_r + (size_t)l * 64,
                                    feat, el, er, N);
    k_aggr<<<(N + 3) / 4, 256, 0, stream>>>(feat, el, er, row_ptr, csr_src, mask,
                                            0, 1, outs[l], N);
  }

  // --- MLP head ---
  k_mlp<<<dgb, 256, 0, stream>>>(out0, out1, out2, out3, W0, b0,
                                 W1, b1, W2, b2, out, N);
}

// Round 6
// 476.167 us; speedup vs baseline: 1.1986x; 1.1559x over previous
//
#include <hip/hip_runtime.h>
#include <math.h>

// ---------------------------------------------------------------------------
// SNAT3: 4-layer GAT GNN. N=50000, E=800000, HID=64, fp32.
// R13 = R8 structure (453us verified) + weights staged in LDS.
//  Diagnosed laws from R8-R12:
//   - R8: s_load(weights) + ds_read(acts) share lgkmcnt; SMEM returns o-o-o
//     vs DS in-order -> compiler drains lgkmcnt(0) per unroll group ->
//     VALUBusy 15%. Weights must NOT be SMEM in hot loops.
//   - R9: vmem does not dedup same-address lanes -> weights must not be
//     per-lane vmem either. Only LDS broadcasts.
//   - R10/R11/R12: per-lane-row global access (16B/lane at 256-512B lane
//     stride) causes 4-14x HBM amplification (FETCH/WRITE 100-200MB vs
//     13MB legit). Global loads/stores must cover contiguous 64B lines per
//     instruction -> keep R8's r/p staging everywhere.
//  Fix: stage weight matrices into sW (stride 68: 16B-aligned rows ->
//  ds_read_b128; wave-uniform addr -> bank-read broadcast ~free). Hot loop:
//  1 b32 (act, (lane+k)%32 conflict-free) + 4 b128 (weights) per 16 FMA.
//  Numerics bit-identical to R8 (same values, same FMA order).
// ---------------------------------------------------------------------------

__global__ void k_zero(int* __restrict__ counts, int N) {
  int i = blockIdx.x * 256 + threadIdx.x;
  if (i < N) counts[i] = 0;
}

__global__ void k_hist(const int* __restrict__ dst, int* __restrict__ counts, int E) {
  int e = blockIdx.x * blockDim.x + threadIdx.x;
  if (e < E) atomicAdd(&counts[dst[e]], 1);
}

__global__ __launch_bounds__(1024) void k_bsum(const int* __restrict__ counts,
                                               int* __restrict__ bsum, int n) {
  __shared__ int wsum[16];
  int tid = threadIdx.x, lane = tid & 63, wid = tid >> 6;
  int i = blockIdx.x * 1024 + tid;
  int v = (i < n) ? counts[i] : 0;
  #pragma unroll
  for (int off = 32; off; off >>= 1) v += __shfl_xor(v, off, 64);
  if (lane == 0) wsum[wid] = v;
  __syncthreads();
  if (wid == 0) {
    int w = (lane < 16) ? wsum[lane] : 0;
    #pragma unroll
    for (int off = 8; off; off >>= 1) w += __shfl_xor(w, off, 64);
    if (lane == 0) bsum[blockIdx.x] = w;
  }
}

__global__ __launch_bounds__(64) void k_bscan(const int* __restrict__ bsum,
                                              int* __restrict__ bofs,
                                              int* __restrict__ row_ptr,
                                              int nb, int n) {
  int lane = threadIdx.x;
  int carry = 0;
  for (int base = 0; base < nb; base += 64) {
    int idx = base + lane;
    int orig = (idx < nb) ? bsum[idx] : 0;
    int inc = orig;
    #pragma unroll
    for (int off = 1; off < 64; off <<= 1) {
      int t = __shfl_up(inc, off, 64);
      if (lane >= off) inc += t;
    }
    if (idx < nb) bofs[idx] = carry + inc - orig;
    carry += __shfl(inc, 63, 64);
  }
  if (lane == 0) row_ptr[n] = carry;
}

__global__ __launch_bounds__(1024) void k_scan3(const int* __restrict__ counts,
                                                const int* __restrict__ bofs,
                                                int* __restrict__ row_ptr,
                                                int* __restrict__ cursor, int n) {
  __shared__ int wsum[16];
  int tid = threadIdx.x, lane = tid & 63, wid = tid >> 6;
  int i = blockIdx.x * 1024 + tid;
  int v = (i < n) ? counts[i] : 0;
  int inc = v;
  #pragma unroll
  for (int off = 1; off < 64; off <<= 1) {
    int t = __shfl_up(inc, off, 64);
    if (lane >= off) inc += t;
  }
  if (lane == 63) wsum[wid] = inc;
  __syncthreads();
  if (wid == 0 && lane < 16) {
    int orig = wsum[lane];
    int w = orig;
    #pragma unroll
    for (int off = 1; off < 16; off <<= 1) {
      int t = __shfl_up(w, off, 64);
      if (lane >= off) w += t;
    }
    wsum[lane] = w - orig;
  }
  __syncthreads();
  int excl = bofs[blockIdx.x] + wsum[wid] + inc - v;
  if (i < n) { row_ptr[i] = excl; cursor[i] = excl; }
}

__global__ void k_scatter(const int* __restrict__ src, const int* __restrict__ dst,
                          int* __restrict__ cursor, int* __restrict__ csr_src, int E) {
  int e = blockIdx.x * blockDim.x + threadIdx.x;
  if (e < E) {
    int pos = atomicAdd(&cursor[dst[e]], 1);
    csr_src[pos] = src[e];
  }
}

// ---- dense building blocks ----
#define SWS 68   // sW float stride: rows 272B (16B-aligned) -> ds_read_b128

// stage one 64x64 fp32 row-major matrix into LDS at stride SWS.
// thread k_=tid>>2 p_=tid&3 copies 64B contiguous -> coalesced, no amplif.
#define STAGE_W(DST, SRC)                                            \
  {                                                                  \
    int k_ = threadIdx.x >> 2, p_ = threadIdx.x & 3;                 \
    const float* s_ = (SRC) + k_ * 64 + p_ * 16;                     \
    float* d_ = (DST) + k_ * SWS + p_ * 16;                          \
    _Pragma("unroll")                                                \
    for (int c_ = 0; c_ < 4; c_++)                                   \
      *(float4*)(d_ + c_ * 4) = *(const float4*)(s_ + c_ * 4);       \
  }

// ---- fused: h = tanh(x@We); feat = h@Wg0; el/er.  h never hits global ----
__global__ __launch_bounds__(256, 3) void k_embed_feat(
    const float* __restrict__ x, const float* __restrict__ We,
    const float* __restrict__ Wg, const float* __restrict__ al,
    const float* __restrict__ ar, float* __restrict__ feat,
    float* __restrict__ el, float* __restrict__ er, int N) {
  __shared__ float sA[64 * 129];  // x staging (33KB); reused as 64x65 exchange
  __shared__ float sW[64 * SWS];  // weight slot: We-lo -> We-hi -> Wg
  __shared__ float sE[64 * 8];
  int tid = threadIdx.x, lane = tid & 63, wv = tid >> 6;
  int nb0 = blockIdx.x * 64, nl = N - 1;
  int r = tid >> 2, p = tid & 3;
  {
    const float* gp = x + (size_t)min(nb0 + r, nl) * 128;
    #pragma unroll
    for (int half = 0; half < 2; half++) {
      const float* g = gp + half * 64 + p * 16;
      float4 v0 = *(const float4*)(g + 0), v1 = *(const float4*)(g + 4);
      float4 v2 = *(const float4*)(g + 8), v3 = *(const float4*)(g + 12);
      float* dp = &sA[r * 129 + half * 64 + p * 16];
      dp[0]=v0.x; dp[1]=v0.y; dp[2]=v0.z; dp[3]=v0.w;
      dp[4]=v1.x; dp[5]=v1.y; dp[6]=v1.z; dp[7]=v1.w;
      dp[8]=v2.x; dp[9]=v2.y; dp[10]=v2.z; dp[11]=v2.w;
      dp[12]=v3.x; dp[13]=v3.y; dp[14]=v3.z; dp[15]=v3.w;
    }
  }
  STAGE_W(sW, We);                 // We rows 0..63
  __syncthreads();
  int f0 = __builtin_amdgcn_readfirstlane(wv * 16);
  float acc[16];
  #pragma unroll
  for (int f = 0; f < 16; f++) acc[f] = 0.f;
  // GEMM1a: k 0..63 with sW = We rows 0..63
  #pragma unroll 4
  for (int k = 0; k < 64; k++) {
    float ak = sA[lane * 129 + k];
    const float* wr = &sW[k * SWS + f0];
    float w[16];
    *(float4*)&w[0]  = *(const float4*)(wr + 0);
    *(float4*)&w[4]  = *(const float4*)(wr + 4);
    *(float4*)&w[8]  = *(const float4*)(wr + 8);
    *(float4*)&w[12] = *(const float4*)(wr + 12);
    #pragma unroll
    for (int f = 0; f < 16; f++) acc[f] = fmaf(ak, w[f], acc[f]);
  }
  __syncthreads();                 // GEMM1a reads of sW done
  STAGE_W(sW, We + 4096);          // We rows 64..127
  __syncthreads();
  #pragma unroll 4
  for (int k = 0; k < 64; k++) {
    float ak = sA[lane * 129 + 64 + k];
    const float* wr = &sW[k * SWS + f0];
    float w[16];
    *(float4*)&w[0]  = *(const float4*)(wr + 0);
    *(float4*)&w[4]  = *(const float4*)(wr + 4);
    *(float4*)&w[8]  = *(const float4*)(wr + 8);
    *(float4*)&w[12] = *(const float4*)(wr + 12);
    #pragma unroll
    for (int f = 0; f < 16; f++) acc[f] = fmaf(ak, w[f], acc[f]);
  }
  __syncthreads();                 // x reads + GEMM1b sW reads done
  STAGE_W(sW, Wg);                 // Wg for the feat GEMM
  #pragma unroll
  for (int f = 0; f < 16; f++) sA[lane * 65 + f0 + f] = tanhf(acc[f]);
  __syncthreads();
  float acc2[16];
  #pragma unroll
  for (int f = 0; f < 16; f++) acc2[f] = 0.f;
  #pragma unroll 4
  for (int k = 0; k < 64; k++) {
    float ak = sA[lane * 65 + k];
    const float* wr = &sW[k * SWS + f0];
    float w[16];
    *(float4*)&w[0]  = *(const float4*)(wr + 0);
    *(float4*)&w[4]  = *(const float4*)(wr + 4);
    *(float4*)&w[8]  = *(const float4*)(wr + 8);
    *(float4*)&w[12] = *(const float4*)(wr + 12);
    #pragma unroll
    for (int f = 0; f < 16; f++) acc2[f] = fmaf(ak, w[f], acc2[f]);
  }
  float rl = 0.f, rr = 0.f;
  #pragma unroll
  for (int f = 0; f < 16; f++) {
    rl = fmaf(acc2[f], al[f0 + f], rl);
    rr = fmaf(acc2[f], ar[f0 + f], rr);
  }
  sE[lane * 8 + wv] = rl;
  sE[lane * 8 + 4 + wv] = rr;
  __syncthreads();  // all h reads done; safe to overwrite sA
  #pragma unroll
  for (int f = 0; f < 16; f++) sA[lane * 65 + f0 + f] = acc2[f];
  __syncthreads();
  {
    int n = nb0 + r;
    if (n < N) {
      const float* sp = &sA[r * 65 + p * 16];
      float* gp = feat + (size_t)n * 64 + p * 16;
      #pragma unroll
      for (int q = 0; q < 4; q++)
        *(float4*)(gp + q * 4) = make_float4(sp[q*4+0], sp[q*4+1], sp[q*4+2], sp[q*4+3]);
    }
  }
  if (tid < 64) {
    int n = nb0 + tid;
    if (n < N) {
      el[n] = (sE[tid*8+0] + sE[tid*8+1]) + (sE[tid*8+2] + sE[tid*8+3]);
      er[n] = (sE[tid*8+4] + sE[tid*8+5]) + (sE[tid*8+6] + sE[tid*8+7]);
    }
  }
}

// ---- feat = hin @ Wg; el/er (layers 1..3) ----
__global__ __launch_bounds__(256, 3) void k_feat(const float* __restrict__ hin,
                                                 const float* __restrict__ Wg,
                                                 const float* __restrict__ al,
                                                 const float* __restrict__ ar,
                                                 float* __restrict__ feat,
                                                 float* __restrict__ el,
                                                 float* __restrict__ er, int N) {
  __shared__ float sA[64 * 65];
  __shared__ float sW[64 * SWS];
  __shared__ float sE[64 * 8];
  int tid = threadIdx.x, lane = tid & 63, wv = tid >> 6;
  int nb0 = blockIdx.x * 64;
  int nl = N - 1;
  int r = tid >> 2, p = tid & 3;
  {
    const float* g = hin + (size_t)min(nb0 + r, nl) * 64 + p * 16;
    float4 v0 = *(const float4*)(g + 0), v1 = *(const float4*)(g + 4);
    float4 v2 = *(const float4*)(g + 8), v3 = *(const float4*)(g + 12);
    float* dp = &sA[r * 65 + p * 16];
    dp[0]=v0.x; dp[1]=v0.y; dp[2]=v0.z; dp[3]=v0.w;
    dp[4]=v1.x; dp[5]=v1.y; dp[6]=v1.z; dp[7]=v1.w;
    dp[8]=v2.x; dp[9]=v2.y; dp[10]=v2.z; dp[11]=v2.w;
    dp[12]=v3.x; dp[13]=v3.y; dp[14]=v3.z; dp[15]=v3.w;
  }
  STAGE_W(sW, Wg);
  __syncthreads();
  int f0 = __builtin_amdgcn_readfirstlane(wv * 16);
  float acc[16];
  #pragma unroll
  for (int f = 0; f < 16; f++) acc[f] = 0.f;
  #pragma unroll 4
  for (int k = 0; k < 64; k++) {
    float ak = sA[lane * 65 + k];
    const float* wr = &sW[k * SWS + f0];
    float w[16];
    *(float4*)&w[0]  = *(const float4*)(wr + 0);
    *(float4*)&w[4]  = *(const float4*)(wr + 4);
    *(float4*)&w[8]  = *(const float4*)(wr + 8);
    *(float4*)&w[12] = *(const float4*)(wr + 12);
    #pragma unroll
    for (int f = 0; f < 16; f++) acc[f] = fmaf(ak, w[f], acc[f]);
  }
  float rl = 0.f, rr = 0.f;
  #pragma unroll
  for (int f = 0; f < 16; f++) {
    rl = fmaf(acc[f], al[f0 + f], rl);
    rr = fmaf(acc[f], ar[f0 + f], rr);
  }
  __syncthreads();
  #pragma unroll
  for (int f = 0; f < 16; f++) sA[lane * 65 + f0 + f] = acc[f];
  sE[lane * 8 + wv] = rl;
  sE[lane * 8 + 4 + wv] = rr;
  __syncthreads();
  {
    int n = nb0 + r;
    if (n < N) {
      const float* sp = &sA[r * 65 + p * 16];
      float* gp = feat + (size_t)n * 64 + p * 16;
      #pragma unroll
      for (int q = 0; q < 4; q++)
        *(float4*)(gp + q * 4) = make_float4(sp[q*4+0], sp[q*4+1], sp[q*4+2], sp[q*4+3]);
    }
  }
  if (tid < 64) {
    int n = nb0 + tid;
    if (n < N) {
      el[n] = (sE[tid*8+0] + sE[tid*8+1]) + (sE[tid*8+2] + sE[tid*8+3]);
      er[n] = (sE[tid*8+4] + sE[tid*8+5]) + (sE[tid*8+6] + sE[tid*8+7]);
    }
  }
}

// ---- edge softmax + aggregate: one wave per dst node, lane = feature ----
__global__ __launch_bounds__(256) void k_aggr(const float* __restrict__ feat,
                                              const float* __restrict__ el,
                                              const float* __restrict__ er,
                                              const int* __restrict__ row_ptr,
                                              const int* __restrict__ csr_src,
                                              unsigned char* __restrict__ mask,
                                              int write_mask, int use_mask,
                                              float* __restrict__ hout, int N) {
  __shared__ __align__(16) int   su[4][64];
  __shared__ __align__(16) float spl[4][64];
  int wv = (int)((blockIdx.x * blockDim.x + threadIdx.x) >> 6);
  int wave = threadIdx.x >> 6, lane = threadIdx.x & 63;
  if (wv >= N) return;
  int beg = row_ptr[wv], end = row_ptr[wv + 1];
  int deg = end - beg;
  float erv = er[wv];
  float acc0 = 0.f, acc1 = 0.f, acc2 = 0.f, acc3 = 0.f;
  if (deg <= 64) {
    int k = beg + lane;
    bool have = (lane < deg);
    int u = have ? csr_src[k] : 0;
    float sc = -INFINITY;
    if (have) {
      float e0 = el[u] + erv;
      sc = (e0 >= 0.f) ? e0 : 0.2f * e0;
      if (use_mask && mask[k] == 0) sc = -1e9f;
    }
    float m = sc;
    #pragma unroll
    for (int off = 32; off; off >>= 1) m = fmaxf(m, __shfl_xor(m, off, 64));
    float pl = have ? expf(sc - m) : 0.f;
    float s = pl;
    #pragma unroll
    for (int off = 32; off; off >>= 1) s += __shfl_xor(s, off, 64);
    pl *= 1.0f / fmaxf(s, 1e-9f);
    if (write_mask && have) mask[k] = (pl >= 0.01f) ? 1 : 0;
    su[wave][lane] = u;
    spl[wave][lane] = pl;
    int dq = (deg + 3) >> 2;
    #pragma unroll 2
    for (int q = 0; q < dq; q++) {
      int4   uu = *(const int4*)&su[wave][q * 4];
      float4 pp = *(const float4*)&spl[wave][q * 4];
      acc0 = fmaf(pp.x, feat[(size_t)uu.x * 64 + lane], acc0);
      acc1 = fmaf(pp.y, feat[(size_t)uu.y * 64 + lane], acc1);
      acc2 = fmaf(pp.z, feat[(size_t)uu.z * 64 + lane], acc2);
      acc3 = fmaf(pp.w, feat[(size_t)uu.w * 64 + lane], acc3);
    }
  } else {
    float m = -INFINITY, s = 0.f;
    for (int base = beg; base < end; base += 64) {
      int k = base + lane;
      float sc = -INFINITY;
      if (k < end) {
        int u = csr_src[k];
        float e0 = el[u] + erv;
        sc = (e0 >= 0.f) ? e0 : 0.2f * e0;
        if (use_mask && mask[k] == 0) sc = -1e9f;
      }
      float cm = sc;
      #pragma unroll
      for (int off = 32; off; off >>= 1) cm = fmaxf(cm, __shfl_xor(cm, off, 64));
      float nm = fmaxf(m, cm);
      float t = (k < end) ? expf(sc - nm) : 0.f;
      #pragma unroll
      for (int off = 32; off; off >>= 1) t += __shfl_xor(t, off, 64);
      s = s * expf(m - nm) + t;
      m = nm;
    }
    float inv = 1.0f / fmaxf(s, 1e-9f);
    for (int base = beg; base < end; base += 64) {
      int k = base + lane;
      int u = 0;
      float pl = 0.f;
      if (k < end) {
        u = csr_src[k];
        float e0 = el[u] + erv;
        float sc = (e0 >= 0.f) ? e0 : 0.2f * e0;
        if (use_mask && mask[k] == 0) sc = -1e9f;
        pl = expf(sc - m) * inv;
        if (write_mask) mask[k] = (pl >= 0.01f) ? 1 : 0;
      }
      su[wave][lane] = u;
      spl[wave][lane] = pl;
      int cnt = min(64, end - base);
      int dq = (cnt + 3) >> 2;
      for (int q = 0; q < dq; q++) {
        int4   uu = *(const int4*)&su[wave][q * 4];
        float4 pp = *(const float4*)&spl[wave][q * 4];
        acc0 = fmaf(pp.x, feat[(size_t)uu.x * 64 + lane], acc0);
        acc1 = fmaf(pp.y, feat[(size_t)uu.y * 64 + lane], acc1);
        acc2 = fmaf(pp.z, feat[(size_t)uu.z * 64 + lane], acc2);
        acc3 = fmaf(pp.w, feat[(size_t)uu.w * 64 + lane], acc3);
      }
    }
  }
  float acc = (acc0 + acc1) + (acc2 + acc3);
  hout[(size_t)wv * 64 + lane] = (acc > 0.f) ? acc : expm1f(acc);
}

// ---- fused MLP head: block=64 nodes, wave=16-feature chunk ----
__global__ __launch_bounds__(256, 3) void k_mlp(const float* __restrict__ o0,
                                                const float* __restrict__ o1,
                                                const float* __restrict__ o2,
                                                const float* __restrict__ o3,
                                                const float* __restrict__ W0,
                                                const float* __restrict__ b0,
                                                const float* __restrict__ W1,
                                                const float* __restrict__ b1,
                                                const float* __restrict__ W2,
                                                const float* __restrict__ b2,
                                                float* __restrict__ out, int N) {
  __shared__ float sA[64 * 65];   // staged seg acts; reused as L0-out exchange
  __shared__ float sW[64 * SWS];  // W0 seg / W1 slot
  __shared__ float sR[64 * 5];    // layer-2 partials [node][wave]
  int tid = threadIdx.x, lane = tid & 63, wv = tid >> 6;
  int nb0 = blockIdx.x * 64;
  int nl = N - 1;
  int f0 = __builtin_amdgcn_readfirstlane(wv * 16);
  float acc[16];
  #pragma unroll
  for (int f = 0; f < 16; f++) acc[f] = b0[f0 + f];
  int r = tid >> 2, p = tid & 3;

  auto seg = [&](const float* __restrict__ sp, const float* __restrict__ wp) {
    __syncthreads();   // prior iter's sA/sW reads complete before restage
    {
      const float* g = sp + (size_t)min(nb0 + r, nl) * 64 + p * 16;
      float4 v0 = *(const float4*)(g + 0), v1 = *(const float4*)(g + 4);
      float4 v2 = *(const float4*)(g + 8), v3 = *(const float4*)(g + 12);
      float* dp = &sA[r * 65 + p * 16];
      dp[0]=v0.x; dp[1]=v0.y; dp[2]=v0.z; dp[3]=v0.w;
      dp[4]=v1.x; dp[5]=v1.y; dp[6]=v1.z; dp[7]=v1.w;
      dp[8]=v2.x; dp[9]=v2.y; dp[10]=v2.z; dp[11]=v2.w;
      dp[12]=v3.x; dp[13]=v3.y; dp[14]=v3.z; dp[15]=v3.w;
    }
    STAGE_W(sW, wp);
    __syncthreads();
    #pragma unroll 4
    for (int k = 0; k < 64; k++) {
      float ak = sA[lane * 65 + k];
      const float* wr = &sW[k * SWS + f0];
      float w[16];
      *(float4*)&w[0]  = *(const float4*)(wr + 0);
      *(float4*)&w[4]  = *(const float4*)(wr + 4);
      *(float4*)&w[8]  = *(const float4*)(wr + 8);
      *(float4*)&w[12] = *(const float4*)(wr + 12);
      #pragma unroll
      for (int f = 0; f < 16; f++) acc[f] = fmaf(ak, w[f], acc[f]);
    }
  };
  seg(o0, W0);
  seg(o1, W0 + 64 * 64);
  seg(o2, W0 + 128 * 64);
  seg(o3, W0 + 192 * 64);

  // layer-0 relu -> cross-wave exchange (reuse sA), stage W1
  __syncthreads();
  STAGE_W(sW, W1);
  #pragma unroll
  for (int f = 0; f < 16; f++)
    sA[lane * 65 + f0 + f] = (acc[f] > 0.f) ? acc[f] : 0.f;
  __syncthreads();
  float a1[16];
  #pragma unroll
  for (int f = 0; f < 16; f++) a1[f] = b1[f0 + f];
  #pragma unroll 4
  for (int k = 0; k < 64; k++) {
    float ak = sA[lane * 65 + k];
    const float* wr = &sW[k * SWS + f0];
    float w[16];
    *(float4*)&w[0]  = *(const float4*)(wr + 0);
    *(float4*)&w[4]  = *(const float4*)(wr + 4);
    *(float4*)&w[8]  = *(const float4*)(wr + 8);
    *(float4*)&w[12] = *(const float4*)(wr + 12);
    #pragma unroll
    for (int f = 0; f < 16; f++) a1[f] = fmaf(ak, w[f], a1[f]);
  }
  float rp = 0.f;
  #pragma unroll
  for (int f = 0; f < 16; f++) {
    float t = (a1[f] > 0.f) ? a1[f] : 0.f;
    rp = fmaf(t, W2[f0 + f], rp);
  }
  sR[lane * 5 + wv] = rp;
  __syncthreads();
  if (tid < 64) {
    int n = nb0 + tid;
    if (n < N) {
      float o = (sR[tid*5+0] + sR[tid*5+1]) + (sR[tid*5+2] + sR[tid*5+3]) + b2[0];
      out[n] = (o > 0.f) ? o : 0.f;
    }
  }
}

extern "C" void kernel_launch(void* const* d_in, const int* in_sizes, int n_in,
                              void* d_out, int out_size, void* d_ws, size_t ws_size,
                              hipStream_t stream) {
  const float* x       = (const float*)d_in[0];
  const int*   esrc    = (const int*)d_in[1];
  const int*   edst    = (const int*)d_in[2];
  const float* W_embed = (const float*)d_in[3];
  const float* W_gat   = (const float*)d_in[4];
  const float* a_l     = (const float*)d_in[5];
  const float* a_r     = (const float*)d_in[6];
  const float* W0      = (const float*)d_in[7];
  const float* b0      = (const float*)d_in[8];
  const float* W1      = (const float*)d_in[9];
  const float* b1      = (const float*)d_in[10];
  const float* W2      = (const float*)d_in[11];
  const float* b2      = (const float*)d_in[12];
  float* out = (float*)d_out;
  const int N = in_sizes[0] / 128;
  const int E = in_sizes[1];

  char* p = (char*)d_ws;
  auto alloc = [&](size_t bytes) -> char* {
    char* r = p;
    p += (bytes + 255) & ~(size_t)255;
    return r;
  };
  float* out0 = (float*)alloc((size_t)N * 64 * 4);
  float* out1 = (float*)alloc((size_t)N * 64 * 4);
  float* out2 = (float*)alloc((size_t)N * 64 * 4);
  float* out3 = (float*)alloc((size_t)N * 64 * 4);
  float* feat = (float*)alloc((size_t)N * 64 * 4);
  float* el   = (float*)alloc((size_t)N * 4);
  float* er   = (float*)alloc((size_t)N * 4);
  int* counts  = (int*)alloc((size_t)N * 4);
  int* row_ptr = (int*)alloc((size_t)(N + 1) * 4);
  int* cursor  = (int*)alloc((size_t)N * 4);
  int* csr_src = (int*)alloc((size_t)E * 4);
  unsigned char* mask = (unsigned char*)alloc((size_t)E);
  int nb = (N + 1023) / 1024;
  int* bsum = (int*)alloc((size_t)nb * 4);
  int* bofs = (int*)alloc((size_t)nb * 4);

  // --- CSR build (dst-sorted) ---
  k_zero<<<(N + 255) / 256, 256, 0, stream>>>(counts, N);
  k_hist<<<(E + 255) / 256, 256, 0, stream>>>(edst, counts, E);
  k_bsum<<<nb, 1024, 0, stream>>>(counts, bsum, N);
  k_bscan<<<1, 64, 0, stream>>>(bsum, bofs, row_ptr, nb, N);
  k_scan3<<<nb, 1024, 0, stream>>>(counts, bofs, row_ptr, cursor, N);
  k_scatter<<<(E + 255) / 256, 256, 0, stream>>>(esrc, edst, cursor, csr_src, E);

  // --- dense grid: 64 nodes per 256-thread block ---
  int dgb = (N + 63) / 64;

  // --- layer 0: fused embed + feat ---
  k_embed_feat<<<dgb, 256, 0, stream>>>(x, W_embed, W_gat,
                                        a_l, a_r, feat, el, er, N);
  float* outs[4] = {out0, out1, out2, out3};
  k_aggr<<<(N + 3) / 4, 256, 0, stream>>>(feat, el, er, row_ptr, csr_src, mask,
                                          1, 0, out0, N);

  // --- layers 1..3 ---
  for (int l = 1; l < 4; l++) {
    k_feat<<<dgb, 256, 0, stream>>>(outs[l - 1], W_gat + (size_t)l * 4096,
                                    a_l + (size_t)l * 64, a_r + (size_t)l * 64,
                                    feat, el, er, N);
    k_aggr<<<(N + 3) / 4, 256, 0, stream>>>(feat, el, er, row_ptr, csr_src, mask,
                                            0, 1, outs[l], N);
  }

  // --- MLP head ---
  k_mlp<<<dgb, 256, 0, stream>>>(out0, out1, out2, out3, W0, b0,
                                 W1, b1, W2, b2, out, N);
}

// Round 7
// 452.565 us; speedup vs baseline: 1.2611x; 1.0522x over previous
//
#include <hip/hip_runtime.h>
#include <math.h>

// ---------------------------------------------------------------------------
// SNAT3: 4-layer GAT GNN. N=50000, E=800000, HID=64, fp32.
// R14 = R13 skeleton + 2D register tiling (acc[4][4]) in the dense GEMMs.
//  R13 diagnosis: LDS broadcast dedups CONFLICTS not BANDWIDTH. Wave-uniform
//  ds_read_b128 still returns 1024B through the 128B/cyc pipe. Per k-step:
//  4x1024B weights (16x redundant) + 256B acts = 4.25 B/FMA -> LDS-BW-bound
//  4x (k_mlp 59us vs 13us VALU floor, VALUBusy 24%).
//  Fix: lane=(nr=lane>>2, fc=lane&3); thread = 4 nodes {nr+16m} x 4 feats
//  {f0+4fc+j}. Per k: 4 b32 acts (16 addrs x 4-lane bcast, conflict-free)
//  + 1 b128 weights = 2048B per wave-k for 1024 FMAs = 2.0 B/FMA.
//  k-accumulation order unchanged -> feat bit-identical to R13; el/er/out
//  reductions use quad shfl-trees (order change ~1e-7, tolerance 1e-5).
//  All staging / exchange / global access patterns from R13 kept verbatim
//  (laws: no SMEM in hot loops; vmem doesn't dedup; 64B-contiguous global).
// ---------------------------------------------------------------------------

__global__ void k_zero(int* __restrict__ counts, int N) {
  int i = blockIdx.x * 256 + threadIdx.x;
  if (i < N) counts[i] = 0;
}

__global__ void k_hist(const int* __restrict__ dst, int* __restrict__ counts, int E) {
  int e = blockIdx.x * blockDim.x + threadIdx.x;
  if (e < E) atomicAdd(&counts[dst[e]], 1);
}

__global__ __launch_bounds__(1024) void k_bsum(const int* __restrict__ counts,
                                               int* __restrict__ bsum, int n) {
  __shared__ int wsum[16];
  int tid = threadIdx.x, lane = tid & 63, wid = tid >> 6;
  int i = blockIdx.x * 1024 + tid;
  int v = (i < n) ? counts[i] : 0;
  #pragma unroll
  for (int off = 32; off; off >>= 1) v += __shfl_xor(v, off, 64);
  if (lane == 0) wsum[wid] = v;
  __syncthreads();
  if (wid == 0) {
    int w = (lane < 16) ? wsum[lane] : 0;
    #pragma unroll
    for (int off = 8; off; off >>= 1) w += __shfl_xor(w, off, 64);
    if (lane == 0) bsum[blockIdx.x] = w;
  }
}

__global__ __launch_bounds__(64) void k_bscan(const int* __restrict__ bsum,
                                              int* __restrict__ bofs,
                                              int* __restrict__ row_ptr,
                                              int nb, int n) {
  int lane = threadIdx.x;
  int carry = 0;
  for (int base = 0; base < nb; base += 64) {
    int idx = base + lane;
    int orig = (idx < nb) ? bsum[idx] : 0;
    int inc = orig;
    #pragma unroll
    for (int off = 1; off < 64; off <<= 1) {
      int t = __shfl_up(inc, off, 64);
      if (lane >= off) inc += t;
    }
    if (idx < nb) bofs[idx] = carry + inc - orig;
    carry += __shfl(inc, 63, 64);
  }
  if (lane == 0) row_ptr[n] = carry;
}

__global__ __launch_bounds__(1024) void k_scan3(const int* __restrict__ counts,
                                                const int* __restrict__ bofs,
                                                int* __restrict__ row_ptr,
                                                int* __restrict__ cursor, int n) {
  __shared__ int wsum[16];
  int tid = threadIdx.x, lane = tid & 63, wid = tid >> 6;
  int i = blockIdx.x * 1024 + tid;
  int v = (i < n) ? counts[i] : 0;
  int inc = v;
  #pragma unroll
  for (int off = 1; off < 64; off <<= 1) {
    int t = __shfl_up(inc, off, 64);
    if (lane >= off) inc += t;
  }
  if (lane == 63) wsum[wid] = inc;
  __syncthreads();
  if (wid == 0 && lane < 16) {
    int orig = wsum[lane];
    int w = orig;
    #pragma unroll
    for (int off = 1; off < 16; off <<= 1) {
      int t = __shfl_up(w, off, 64);
      if (lane >= off) w += t;
    }
    wsum[lane] = w - orig;
  }
  __syncthreads();
  int excl = bofs[blockIdx.x] + wsum[wid] + inc - v;
  if (i < n) { row_ptr[i] = excl; cursor[i] = excl; }
}

__global__ void k_scatter(const int* __restrict__ src, const int* __restrict__ dst,
                          int* __restrict__ cursor, int* __restrict__ csr_src, int E) {
  int e = blockIdx.x * blockDim.x + threadIdx.x;
  if (e < E) {
    int pos = atomicAdd(&cursor[dst[e]], 1);
    csr_src[pos] = src[e];
  }
}

// ---- dense building blocks ----
#define SWS 68   // sW float stride: rows 272B (16B-aligned) -> ds_read_b128

// stage one 64x64 fp32 row-major matrix into LDS at stride SWS (coalesced)
#define STAGE_W(DST, SRC)                                            \
  {                                                                  \
    int k_ = threadIdx.x >> 2, p_ = threadIdx.x & 3;                 \
    const float* s_ = (SRC) + k_ * 64 + p_ * 16;                     \
    float* d_ = (DST) + k_ * SWS + p_ * 16;                          \
    _Pragma("unroll")                                                \
    for (int c_ = 0; c_ < 4; c_++)                                   \
      *(float4*)(d_ + c_ * 4) = *(const float4*)(s_ + c_ * 4);       \
  }

// 2D-tiled 64-k GEMM: ACC[4][4] += acts x sW. Thread = nodes {nr+16m} x
// feats {fq+j}. Per k: 4 ds_read_b32 acts + 1 ds_read_b128 weights.
#define GEMM64(ACC, ABASE, ASTRIDE, KOFF)                            \
  { _Pragma("unroll 4")                                              \
    for (int k_ = 0; k_ < 64; k_++) {                                \
      float4 w4_ = *(const float4*)&sW[k_ * SWS + fq];               \
      float a0_ = (ABASE)[(nr +  0) * (ASTRIDE) + (KOFF) + k_];      \
      float a1_ = (ABASE)[(nr + 16) * (ASTRIDE) + (KOFF) + k_];      \
      float a2_ = (ABASE)[(nr + 32) * (ASTRIDE) + (KOFF) + k_];      \
      float a3_ = (ABASE)[(nr + 48) * (ASTRIDE) + (KOFF) + k_];      \
      ACC[0][0] = fmaf(a0_, w4_.x, ACC[0][0]);                       \
      ACC[0][1] = fmaf(a0_, w4_.y, ACC[0][1]);                       \
      ACC[0][2] = fmaf(a0_, w4_.z, ACC[0][2]);                       \
      ACC[0][3] = fmaf(a0_, w4_.w, ACC[0][3]);                       \
      ACC[1][0] = fmaf(a1_, w4_.x, ACC[1][0]);                       \
      ACC[1][1] = fmaf(a1_, w4_.y, ACC[1][1]);                       \
      ACC[1][2] = fmaf(a1_, w4_.z, ACC[1][2]);                       \
      ACC[1][3] = fmaf(a1_, w4_.w, ACC[1][3]);                       \
      ACC[2][0] = fmaf(a2_, w4_.x, ACC[2][0]);                       \
      ACC[2][1] = fmaf(a2_, w4_.y, ACC[2][1]);                       \
      ACC[2][2] = fmaf(a2_, w4_.z, ACC[2][2]);                       \
      ACC[2][3] = fmaf(a2_, w4_.w, ACC[2][3]);                       \
      ACC[3][0] = fmaf(a3_, w4_.x, ACC[3][0]);                       \
      ACC[3][1] = fmaf(a3_, w4_.y, ACC[3][1]);                       \
      ACC[3][2] = fmaf(a3_, w4_.z, ACC[3][2]);                       \
      ACC[3][3] = fmaf(a3_, w4_.w, ACC[3][3]);                       \
    } }

// ---- fused: h = tanh(x@We); feat = h@Wg0; el/er.  h never hits global ----
__global__ __launch_bounds__(256, 3) void k_embed_feat(
    const float* __restrict__ x, const float* __restrict__ We,
    const float* __restrict__ Wg, const float* __restrict__ al,
    const float* __restrict__ ar, float* __restrict__ feat,
    float* __restrict__ el, float* __restrict__ er, int N) {
  __shared__ float sA[64 * 129];  // x staging (33KB); reused as 64x65 exchange
  __shared__ float sW[64 * SWS];  // weight slot: We-lo -> We-hi -> Wg
  __shared__ float sE[64 * 8];
  int tid = threadIdx.x, lane = tid & 63, wv = tid >> 6;
  int nb0 = blockIdx.x * 64, nl = N - 1;
  int r = tid >> 2, p = tid & 3;
  int nr = lane >> 2, fc = lane & 3;
  int fq = wv * 16 + fc * 4;
  {
    const float* gp = x + (size_t)min(nb0 + r, nl) * 128;
    #pragma unroll
    for (int half = 0; half < 2; half++) {
      const float* g = gp + half * 64 + p * 16;
      float4 v0 = *(const float4*)(g + 0), v1 = *(const float4*)(g + 4);
      float4 v2 = *(const float4*)(g + 8), v3 = *(const float4*)(g + 12);
      float* dp = &sA[r * 129 + half * 64 + p * 16];
      dp[0]=v0.x; dp[1]=v0.y; dp[2]=v0.z; dp[3]=v0.w;
      dp[4]=v1.x; dp[5]=v1.y; dp[6]=v1.z; dp[7]=v1.w;
      dp[8]=v2.x; dp[9]=v2.y; dp[10]=v2.z; dp[11]=v2.w;
      dp[12]=v3.x; dp[13]=v3.y; dp[14]=v3.z; dp[15]=v3.w;
    }
  }
  STAGE_W(sW, We);                 // We rows 0..63
  __syncthreads();
  float acc[4][4];
  #pragma unroll
  for (int m = 0; m < 4; m++)
    #pragma unroll
    for (int j = 0; j < 4; j++) acc[m][j] = 0.f;
  GEMM64(acc, sA, 129, 0);         // k 0..63
  __syncthreads();                 // GEMM1a sW reads done
  STAGE_W(sW, We + 4096);          // We rows 64..127
  __syncthreads();
  GEMM64(acc, sA, 129, 64);        // k 64..127
  __syncthreads();                 // x reads + GEMM1b sW reads done
  STAGE_W(sW, Wg);                 // Wg for the feat GEMM
  #pragma unroll
  for (int m = 0; m < 4; m++)
    #pragma unroll
    for (int j = 0; j < 4; j++)
      sA[(nr + 16 * m) * 65 + fq + j] = tanhf(acc[m][j]);
  __syncthreads();
  float acc2[4][4];
  #pragma unroll
  for (int m = 0; m < 4; m++)
    #pragma unroll
    for (int j = 0; j < 4; j++) acc2[m][j] = 0.f;
  GEMM64(acc2, sA, 65, 0);
  // el/er: 4-f dot per thread, quad tree over fc, fc==0 writes per node
  {
    float alv[4], arv[4];
    *(float4*)&alv[0] = *(const float4*)(al + fq);
    *(float4*)&arv[0] = *(const float4*)(ar + fq);
    #pragma unroll
    for (int m = 0; m < 4; m++) {
      float pl = 0.f, pr = 0.f;
      #pragma unroll
      for (int j = 0; j < 4; j++) {
        pl = fmaf(acc2[m][j], alv[j], pl);
        pr = fmaf(acc2[m][j], arv[j], pr);
      }
      pl += __shfl_xor(pl, 1, 64); pl += __shfl_xor(pl, 2, 64);
      pr += __shfl_xor(pr, 1, 64); pr += __shfl_xor(pr, 2, 64);
      if (fc == 0) {
        sE[(nr + 16 * m) * 8 + wv] = pl;
        sE[(nr + 16 * m) * 8 + 4 + wv] = pr;
      }
    }
  }
  __syncthreads();  // all GEMM2 sA reads done; safe to overwrite exchange
  #pragma unroll
  for (int m = 0; m < 4; m++)
    #pragma unroll
    for (int j = 0; j < 4; j++)
      sA[(nr + 16 * m) * 65 + fq + j] = acc2[m][j];
  __syncthreads();
  {
    int n = nb0 + r;
    if (n < N) {
      const float* sp = &sA[r * 65 + p * 16];
      float* gp = feat + (size_t)n * 64 + p * 16;
      #pragma unroll
      for (int q = 0; q < 4; q++)
        *(float4*)(gp + q * 4) = make_float4(sp[q*4+0], sp[q*4+1], sp[q*4+2], sp[q*4+3]);
    }
  }
  if (tid < 64) {
    int n = nb0 + tid;
    if (n < N) {
      el[n] = (sE[tid*8+0] + sE[tid*8+1]) + (sE[tid*8+2] + sE[tid*8+3]);
      er[n] = (sE[tid*8+4] + sE[tid*8+5]) + (sE[tid*8+6] + sE[tid*8+7]);
    }
  }
}

// ---- feat = hin @ Wg; el/er (layers 1..3) ----
__global__ __launch_bounds__(256, 3) void k_feat(const float* __restrict__ hin,
                                                 const float* __restrict__ Wg,
                                                 const float* __restrict__ al,
                                                 const float* __restrict__ ar,
                                                 float* __restrict__ feat,
                                                 float* __restrict__ el,
                                                 float* __restrict__ er, int N) {
  __shared__ float sA[64 * 65];
  __shared__ float sW[64 * SWS];
  __shared__ float sE[64 * 8];
  int tid = threadIdx.x, lane = tid & 63, wv = tid >> 6;
  int nb0 = blockIdx.x * 64;
  int nl = N - 1;
  int r = tid >> 2, p = tid & 3;
  int nr = lane >> 2, fc = lane & 3;
  int fq = wv * 16 + fc * 4;
  {
    const float* g = hin + (size_t)min(nb0 + r, nl) * 64 + p * 16;
    float4 v0 = *(const float4*)(g + 0), v1 = *(const float4*)(g + 4);
    float4 v2 = *(const float4*)(g + 8), v3 = *(const float4*)(g + 12);
    float* dp = &sA[r * 65 + p * 16];
    dp[0]=v0.x; dp[1]=v0.y; dp[2]=v0.z; dp[3]=v0.w;
    dp[4]=v1.x; dp[5]=v1.y; dp[6]=v1.z; dp[7]=v1.w;
    dp[8]=v2.x; dp[9]=v2.y; dp[10]=v2.z; dp[11]=v2.w;
    dp[12]=v3.x; dp[13]=v3.y; dp[14]=v3.z; dp[15]=v3.w;
  }
  STAGE_W(sW, Wg);
  __syncthreads();
  float acc[4][4];
  #pragma unroll
  for (int m = 0; m < 4; m++)
    #pragma unroll
    for (int j = 0; j < 4; j++) acc[m][j] = 0.f;
  GEMM64(acc, sA, 65, 0);
  // el/er partials
  {
    float alv[4], arv[4];
    *(float4*)&alv[0] = *(const float4*)(al + fq);
    *(float4*)&arv[0] = *(const float4*)(ar + fq);
    #pragma unroll
    for (int m = 0; m < 4; m++) {
      float pl = 0.f, pr = 0.f;
      #pragma unroll
      for (int j = 0; j < 4; j++) {
        pl = fmaf(acc[m][j], alv[j], pl);
        pr = fmaf(acc[m][j], arv[j], pr);
      }
      pl += __shfl_xor(pl, 1, 64); pl += __shfl_xor(pl, 2, 64);
      pr += __shfl_xor(pr, 1, 64); pr += __shfl_xor(pr, 2, 64);
      if (fc == 0) {
        sE[(nr + 16 * m) * 8 + wv] = pl;
        sE[(nr + 16 * m) * 8 + 4 + wv] = pr;
      }
    }
  }
  __syncthreads();  // all GEMM sA reads done; safe to overwrite exchange
  #pragma unroll
  for (int m = 0; m < 4; m++)
    #pragma unroll
    for (int j = 0; j < 4; j++)
      sA[(nr + 16 * m) * 65 + fq + j] = acc[m][j];
  __syncthreads();
  {
    int n = nb0 + r;
    if (n < N) {
      const float* sp = &sA[r * 65 + p * 16];
      float* gp = feat + (size_t)n * 64 + p * 16;
      #pragma unroll
      for (int q = 0; q < 4; q++)
        *(float4*)(gp + q * 4) = make_float4(sp[q*4+0], sp[q*4+1], sp[q*4+2], sp[q*4+3]);
    }
  }
  if (tid < 64) {
    int n = nb0 + tid;
    if (n < N) {
      el[n] = (sE[tid*8+0] + sE[tid*8+1]) + (sE[tid*8+2] + sE[tid*8+3]);
      er[n] = (sE[tid*8+4] + sE[tid*8+5]) + (sE[tid*8+6] + sE[tid*8+7]);
    }
  }
}

// ---- edge softmax + aggregate: one wave per dst node, lane = feature ----
__global__ __launch_bounds__(256) void k_aggr(const float* __restrict__ feat,
                                              const float* __restrict__ el,
                                              const float* __restrict__ er,
                                              const int* __restrict__ row_ptr,
                                              const int* __restrict__ csr_src,
                                              unsigned char* __restrict__ mask,
                                              int write_mask, int use_mask,
                                              float* __restrict__ hout, int N) {
  __shared__ __align__(16) int   su[4][64];
  __shared__ __align__(16) float spl[4][64];
  int wv = (int)((blockIdx.x * blockDim.x + threadIdx.x) >> 6);
  int wave = threadIdx.x >> 6, lane = threadIdx.x & 63;
  if (wv >= N) return;
  int beg = row_ptr[wv], end = row_ptr[wv + 1];
  int deg = end - beg;
  float erv = er[wv];
  float acc0 = 0.f, acc1 = 0.f, acc2 = 0.f, acc3 = 0.f;
  if (deg <= 64) {
    int k = beg + lane;
    bool have = (lane < deg);
    int u = have ? csr_src[k] : 0;
    float sc = -INFINITY;
    if (have) {
      float e0 = el[u] + erv;
      sc = (e0 >= 0.f) ? e0 : 0.2f * e0;
      if (use_mask && mask[k] == 0) sc = -1e9f;
    }
    float m = sc;
    #pragma unroll
    for (int off = 32; off; off >>= 1) m = fmaxf(m, __shfl_xor(m, off, 64));
    float pl = have ? expf(sc - m) : 0.f;
    float s = pl;
    #pragma unroll
    for (int off = 32; off; off >>= 1) s += __shfl_xor(s, off, 64);
    pl *= 1.0f / fmaxf(s, 1e-9f);
    if (write_mask && have) mask[k] = (pl >= 0.01f) ? 1 : 0;
    su[wave][lane] = u;
    spl[wave][lane] = pl;
    int dq = (deg + 3) >> 2;
    #pragma unroll 2
    for (int q = 0; q < dq; q++) {
      int4   uu = *(const int4*)&su[wave][q * 4];
      float4 pp = *(const float4*)&spl[wave][q * 4];
      acc0 = fmaf(pp.x, feat[(size_t)uu.x * 64 + lane], acc0);
      acc1 = fmaf(pp.y, feat[(size_t)uu.y * 64 + lane], acc1);
      acc2 = fmaf(pp.z, feat[(size_t)uu.z * 64 + lane], acc2);
      acc3 = fmaf(pp.w, feat[(size_t)uu.w * 64 + lane], acc3);
    }
  } else {
    float m = -INFINITY, s = 0.f;
    for (int base = beg; base < end; base += 64) {
      int k = base + lane;
      float sc = -INFINITY;
      if (k < end) {
        int u = csr_src[k];
        float e0 = el[u] + erv;
        sc = (e0 >= 0.f) ? e0 : 0.2f * e0;
        if (use_mask && mask[k] == 0) sc = -1e9f;
      }
      float cm = sc;
      #pragma unroll
      for (int off = 32; off; off >>= 1) cm = fmaxf(cm, __shfl_xor(cm, off, 64));
      float nm = fmaxf(m, cm);
      float t = (k < end) ? expf(sc - nm) : 0.f;
      #pragma unroll
      for (int off = 32; off; off >>= 1) t += __shfl_xor(t, off, 64);
      s = s * expf(m - nm) + t;
      m = nm;
    }
    float inv = 1.0f / fmaxf(s, 1e-9f);
    for (int base = beg; base < end; base += 64) {
      int k = base + lane;
      int u = 0;
      float pl = 0.f;
      if (k < end) {
        u = csr_src[k];
        float e0 = el[u] + erv;
        float sc = (e0 >= 0.f) ? e0 : 0.2f * e0;
        if (use_mask && mask[k] == 0) sc = -1e9f;
        pl = expf(sc - m) * inv;
        if (write_mask) mask[k] = (pl >= 0.01f) ? 1 : 0;
      }
      su[wave][lane] = u;
      spl[wave][lane] = pl;
      int cnt = min(64, end - base);
      int dq = (cnt + 3) >> 2;
      for (int q = 0; q < dq; q++) {
        int4   uu = *(const int4*)&su[wave][q * 4];
        float4 pp = *(const float4*)&spl[wave][q * 4];
        acc0 = fmaf(pp.x, feat[(size_t)uu.x * 64 + lane], acc0);
        acc1 = fmaf(pp.y, feat[(size_t)uu.y * 64 + lane], acc1);
        acc2 = fmaf(pp.z, feat[(size_t)uu.z * 64 + lane], acc2);
        acc3 = fmaf(pp.w, feat[(size_t)uu.w * 64 + lane], acc3);
      }
    }
  }
  float acc = (acc0 + acc1) + (acc2 + acc3);
  hout[(size_t)wv * 64 + lane] = (acc > 0.f) ? acc : expm1f(acc);
}

// ---- fused MLP head: block=64 nodes ----
__global__ __launch_bounds__(256, 3) void k_mlp(const float* __restrict__ o0,
                                                const float* __restrict__ o1,
                                                const float* __restrict__ o2,
                                                const float* __restrict__ o3,
                                                const float* __restrict__ W0,
                                                const float* __restrict__ b0,
                                                const float* __restrict__ W1,
                                                const float* __restrict__ b1,
                                                const float* __restrict__ W2,
                                                const float* __restrict__ b2,
                                                float* __restrict__ out, int N) {
  __shared__ float sA[64 * 65];   // staged seg acts; reused as L0-out exchange
  __shared__ float sW[64 * SWS];  // W0 seg / W1 slot
  __shared__ float sR[64 * 5];    // layer-2 partials [node][wave]
  int tid = threadIdx.x, lane = tid & 63, wv = tid >> 6;
  int nb0 = blockIdx.x * 64;
  int nl = N - 1;
  int r = tid >> 2, p = tid & 3;
  int nr = lane >> 2, fc = lane & 3;
  int fq = wv * 16 + fc * 4;
  float acc[4][4];
  {
    float4 b0v = *(const float4*)(b0 + fq);
    #pragma unroll
    for (int m = 0; m < 4; m++) {
      acc[m][0] = b0v.x; acc[m][1] = b0v.y;
      acc[m][2] = b0v.z; acc[m][3] = b0v.w;
    }
  }

  auto seg = [&](const float* __restrict__ sp, const float* __restrict__ wp) {
    __syncthreads();   // prior iter's sA/sW reads complete before restage
    {
      const float* g = sp + (size_t)min(nb0 + r, nl) * 64 + p * 16;
      float4 v0 = *(const float4*)(g + 0), v1 = *(const float4*)(g + 4);
      float4 v2 = *(const float4*)(g + 8), v3 = *(const float4*)(g + 12);
      float* dp = &sA[r * 65 + p * 16];
      dp[0]=v0.x; dp[1]=v0.y; dp[2]=v0.z; dp[3]=v0.w;
      dp[4]=v1.x; dp[5]=v1.y; dp[6]=v1.z; dp[7]=v1.w;
      dp[8]=v2.x; dp[9]=v2.y; dp[10]=v2.z; dp[11]=v2.w;
      dp[12]=v3.x; dp[13]=v3.y; dp[14]=v3.z; dp[15]=v3.w;
    }
    STAGE_W(sW, wp);
    __syncthreads();
    GEMM64(acc, sA, 65, 0);
  };
  seg(o0, W0);
  seg(o1, W0 + 64 * 64);
  seg(o2, W0 + 128 * 64);
  seg(o3, W0 + 192 * 64);

  // layer-0 relu -> cross-wave exchange (reuse sA), stage W1
  __syncthreads();
  STAGE_W(sW, W1);
  #pragma unroll
  for (int m = 0; m < 4; m++)
    #pragma unroll
    for (int j = 0; j < 4; j++) {
      float z = acc[m][j];
      sA[(nr + 16 * m) * 65 + fq + j] = (z > 0.f) ? z : 0.f;
    }
  __syncthreads();
  float a1[4][4];
  {
    float4 b1v = *(const float4*)(b1 + fq);
    #pragma unroll
    for (int m = 0; m < 4; m++) {
      a1[m][0] = b1v.x; a1[m][1] = b1v.y;
      a1[m][2] = b1v.z; a1[m][3] = b1v.w;
    }
  }
  GEMM64(a1, sA, 65, 0);
  {
    float4 w2v = *(const float4*)(W2 + fq);
    float w2a[4] = {w2v.x, w2v.y, w2v.z, w2v.w};
    #pragma unroll
    for (int m = 0; m < 4; m++) {
      float rp = 0.f;
      #pragma unroll
      for (int j = 0; j < 4; j++) {
        float t = (a1[m][j] > 0.f) ? a1[m][j] : 0.f;
        rp = fmaf(t, w2a[j], rp);
      }
      rp += __shfl_xor(rp, 1, 64); rp += __shfl_xor(rp, 2, 64);
      if (fc == 0) sR[(nr + 16 * m) * 5 + wv] = rp;
    }
  }
  __syncthreads();
  if (tid < 64) {
    int n = nb0 + tid;
    if (n < N) {
      float o = (sR[tid*5+0] + sR[tid*5+1]) + (sR[tid*5+2] + sR[tid*5+3]) + b2[0];
      out[n] = (o > 0.f) ? o : 0.f;
    }
  }
}

extern "C" void kernel_launch(void* const* d_in, const int* in_sizes, int n_in,
                              void* d_out, int out_size, void* d_ws, size_t ws_size,
                              hipStream_t stream) {
  const float* x       = (const float*)d_in[0];
  const int*   esrc    = (const int*)d_in[1];
  const int*   edst    = (const int*)d_in[2];
  const float* W_embed = (const float*)d_in[3];
  const float* W_gat   = (const float*)d_in[4];
  const float* a_l     = (const float*)d_in[5];
  const float* a_r     = (const float*)d_in[6];
  const float* W0      = (const float*)d_in[7];
  const float* b0      = (const float*)d_in[8];
  const float* W1      = (const float*)d_in[9];
  const float* b1      = (const float*)d_in[10];
  const float* W2      = (const float*)d_in[11];
  const float* b2      = (const float*)d_in[12];
  float* out = (float*)d_out;
  const int N = in_sizes[0] / 128;
  const int E = in_sizes[1];

  char* p = (char*)d_ws;
  auto alloc = [&](size_t bytes) -> char* {
    char* r = p;
    p += (bytes + 255) & ~(size_t)255;
    return r;
  };
  float* out0 = (float*)alloc((size_t)N * 64 * 4);
  float* out1 = (float*)alloc((size_t)N * 64 * 4);
  float* out2 = (float*)alloc((size_t)N * 64 * 4);
  float* out3 = (float*)alloc((size_t)N * 64 * 4);
  float* feat = (float*)alloc((size_t)N * 64 * 4);
  float* el   = (float*)alloc((size_t)N * 4);
  float* er   = (float*)alloc((size_t)N * 4);
  int* counts  = (int*)alloc((size_t)N * 4);
  int* row_ptr = (int*)alloc((size_t)(N + 1) * 4);
  int* cursor  = (int*)alloc((size_t)N * 4);
  int* csr_src = (int*)alloc((size_t)E * 4);
  unsigned char* mask = (unsigned char*)alloc((size_t)E);
  int nb = (N + 1023) / 1024;
  int* bsum = (int*)alloc((size_t)nb * 4);
  int* bofs = (int*)alloc((size_t)nb * 4);

  // --- CSR build (dst-sorted) ---
  k_zero<<<(N + 255) / 256, 256, 0, stream>>>(counts, N);
  k_hist<<<(E + 255) / 256, 256, 0, stream>>>(edst, counts, E);
  k_bsum<<<nb, 1024, 0, stream>>>(counts, bsum, N);
  k_bscan<<<1, 64, 0, stream>>>(bsum, bofs, row_ptr, nb, N);
  k_scan3<<<nb, 1024, 0, stream>>>(counts, bofs, row_ptr, cursor, N);
  k_scatter<<<(E + 255) / 256, 256, 0, stream>>>(esrc, edst, cursor, csr_src, E);

  // --- dense grid: 64 nodes per 256-thread block ---
  int dgb = (N + 63) / 64;

  // --- layer 0: fused embed + feat ---
  k_embed_feat<<<dgb, 256, 0, stream>>>(x, W_embed, W_gat,
                                        a_l, a_r, feat, el, er, N);
  float* outs[4] = {out0, out1, out2, out3};
  k_aggr<<<(N + 3) / 4, 256, 0, stream>>>(feat, el, er, row_ptr, csr_src, mask,
                                          1, 0, out0, N);

  // --- layers 1..3 ---
  for (int l = 1; l < 4; l++) {
    k_feat<<<dgb, 256, 0, stream>>>(outs[l - 1], W_gat + (size_t)l * 4096,
                                    a_l + (size_t)l * 64, a_r + (size_t)l * 64,
                                    feat, el, er, N);
    k_aggr<<<(N + 3) / 4, 256, 0, stream>>>(feat, el, er, row_ptr, csr_src, mask,
                                            0, 1, outs[l], N);
  }

  // --- MLP head ---
  k_mlp<<<dgb, 256, 0, stream>>>(out0, out1, out2, out3, W0, b0,
                                 W1, b1, W2, b2, out, N);
}